// Round 10
// baseline (1827.623 us; speedup 1.0000x reference)
//
#include <hip/hip_runtime.h>
#include <hip/hip_cooperative_groups.h>
#include <math.h>

namespace cg = cooperative_groups;

#define NN 4096
#define NC 512
#define NE 131072

typedef __bf16 bf16x8 __attribute__((ext_vector_type(8)));
typedef float f32x4 __attribute__((ext_vector_type(4)));
typedef unsigned short u16x8 __attribute__((ext_vector_type(8)));

__device__ __forceinline__ unsigned short f2b(float f){
  unsigned u = __float_as_uint(f);
  u += 0x7fffu + ((u >> 16) & 1u);
  return (unsigned short)(u >> 16);
}
__device__ __forceinline__ float b2f(unsigned short h){
  return __uint_as_float(((unsigned)h) << 16);
}
__device__ __forceinline__ float wredsum(float v){
  #pragma unroll
  for (int o = 32; o; o >>= 1) v += __shfl_xor(v, o, 64);
  return v;
}
__device__ __forceinline__ float wredmax(float v){
  #pragma unroll
  for (int o = 32; o; o >>= 1) v = fmaxf(v, __shfl_xor(v, o, 64));
  return v;
}

// ---------------- conversions / transpose ----------------
__global__ __launch_bounds__(256) void k_transconv(const float* __restrict__ src, int R, int C,
    unsigned short* __restrict__ dstT, int ldT, unsigned short* __restrict__ dstD){
  __shared__ unsigned short tile[64][65];
  int bc = blockIdx.x * 64, br = blockIdx.y * 64;
  int t = threadIdx.x, lc = t & 63, lr4 = t >> 6;
  for (int j = 0; j < 16; ++j){
    int r = br + lr4*16 + j, c = bc + lc;
    float v = (r < R && c < C) ? src[(size_t)r*C + c] : 0.f;
    unsigned short b = f2b(v);
    tile[lr4*16+j][lc] = b;
    if (dstD && r < R && c < C) dstD[(size_t)r*C + c] = b;
  }
  __syncthreads();
  for (int j = 0; j < 16; ++j){
    int cc = bc + lr4*16 + j, rr = br + lc;
    if (cc < C && rr < R) dstT[(size_t)cc*ldT + rr] = tile[lc][lr4*16+j];
  }
}

// three 512x512 weight transposes in one launch (blockIdx.z selects matrix)
__global__ __launch_bounds__(256) void k_transconv3(const float* __restrict__ A,
    const float* __restrict__ B, const float* __restrict__ C,
    unsigned short* __restrict__ TA, unsigned short* __restrict__ TB, unsigned short* __restrict__ TC){
  __shared__ unsigned short tile[64][65];
  const float* src = (blockIdx.z == 0) ? A : ((blockIdx.z == 1) ? B : C);
  unsigned short* dstT = (blockIdx.z == 0) ? TA : ((blockIdx.z == 1) ? TB : TC);
  int bc = blockIdx.x * 64, br = blockIdx.y * 64;
  int t = threadIdx.x, lc = t & 63, lr4 = t >> 6;
  for (int j = 0; j < 16; ++j){
    int r = br + lr4*16 + j, c = bc + lc;
    tile[lr4*16+j][lc] = f2b(src[(size_t)r*512 + c]);
  }
  __syncthreads();
  for (int j = 0; j < 16; ++j){
    int cc = bc + lr4*16 + j, rr = br + lc;
    dstT[(size_t)cc*512 + rr] = tile[lc][lr4*16+j];
  }
}

__global__ __launch_bounds__(256) void k_normx(const float* __restrict__ x, unsigned short* __restrict__ nx){
  int wid = threadIdx.x >> 6, lane = threadIdx.x & 63;
  int row = blockIdx.x*4 + wid;
  const float* xr = x + (size_t)row*NC + lane*8;
  float v[8]; float ss = 0.f;
  #pragma unroll
  for (int j=0;j<8;j++){ v[j] = xr[j]; ss += v[j]*v[j]; }
  ss = wredsum(ss);
  float sc = 1.0f / fmaxf(sqrtf(ss), 1e-12f);
  u16x8 o;
  #pragma unroll
  for (int j=0;j<8;j++) o[j] = f2b(v[j]*sc);
  *(u16x8*)(nx + (size_t)row*NC + lane*8) = o;
}

// ---------------- CSR + 1-hop bitset (fused edge pass) ----------------
__global__ void k_count_b1(const int* __restrict__ src, const int* __restrict__ dst,
    int* cin, int* cout, unsigned long long* B1){
  int e = blockIdx.x*256 + threadIdx.x;
  if (e < NE){
    int s = src[e], d = dst[e];
    atomicAdd(&cout[s], 1);
    atomicAdd(&cin[d], 1);
    atomicOr(&B1[(size_t)d*64 + (s>>6)], 1ull << (s & 63));
  }
}
__global__ __launch_bounds__(1024) void k_scan(const int* __restrict__ cnt0, const int* __restrict__ cnt1,
    int* off0, int* off1, int* fill0, int* fill1){
  __shared__ int s[1024];
  int t = threadIdx.x;
  for (int arr = 0; arr < 2; ++arr){
    const int* cnt = arr ? cnt1 : cnt0;
    int* off = arr ? off1 : off0;
    int* fill = arr ? fill1 : fill0;
    int a0 = cnt[t*4], a1 = cnt[t*4+1], a2 = cnt[t*4+2], a3 = cnt[t*4+3];
    int ts = a0+a1+a2+a3;
    s[t] = ts; __syncthreads();
    for (int o = 1; o < 1024; o <<= 1){
      int v = (t >= o) ? s[t-o] : 0; __syncthreads();
      s[t] += v; __syncthreads();
    }
    int ex = s[t] - ts;
    off[t*4] = ex; off[t*4+1] = ex+a0; off[t*4+2] = ex+a0+a1; off[t*4+3] = ex+a0+a1+a2;
    fill[t*4] = ex; fill[t*4+1] = ex+a0; fill[t*4+2] = ex+a0+a1; fill[t*4+3] = ex+a0+a1+a2;
    if (t == 1023) off[4096] = s[1023];
    __syncthreads();
  }
}
__global__ void k_fill(const int* __restrict__ src, const int* __restrict__ dst,
    int* fin, int* fout, int* csr_in, int* csr_out){
  int e = blockIdx.x*256 + threadIdx.x;
  if (e < NE){
    int s = src[e], d = dst[e];
    int pi = atomicAdd(&fin[d], 1);  csr_in[pi] = s;
    int po = atomicAdd(&fout[s], 1); csr_out[po] = d;
  }
}

// ---------------- ego 2-hop bitsets -> dense bf16 Mf ----------------
__global__ __launch_bounds__(256) void k_bits2(const unsigned long long* __restrict__ B1,
    const int* __restrict__ off_in, const int* __restrict__ csr_in,
    unsigned short* __restrict__ Mf, float* __restrict__ rowrecip){
  int wid = threadIdx.x >> 6, lane = threadIdx.x & 63;
  int node = blockIdx.x*4 + wid;
  unsigned long long bits = B1[(size_t)node*64 + lane];
  if (lane == (node >> 6)) bits |= 1ull << (node & 63);
  int beg = off_in[node], end = off_in[node+1];
  for (int e = beg; e < end; ++e){
    int j = csr_in[e];
    bits |= B1[(size_t)j*64 + lane];
  }
  int pc = __popcll(bits);
  #pragma unroll
  for (int o = 32; o; o >>= 1) pc += __shfl_xor(pc, o, 64);
  if (lane == 0) rowrecip[node] = 1.0f / (float)pc;
  unsigned lo = (unsigned)(bits & 0xffffffffull), hi = (unsigned)(bits >> 32);
  unsigned int* Mrow = (unsigned int*)(Mf + (size_t)node*NN);
  for (int k = 0; k < 32; ++k){
    int srcl = 2*k + (lane >> 5);
    unsigned wlo = (unsigned)__shfl((int)lo, srcl, 64);
    unsigned whi = (unsigned)__shfl((int)hi, srcl, 64);
    unsigned long long w2 = ((unsigned long long)whi << 32) | wlo;
    int sh = (lane & 31) * 2;
    unsigned v = (unsigned)((w2 >> sh) & 3ull);
    Mrow[k*64 + lane] = ((v & 1u) ? 0x3F80u : 0u) | ((v & 2u) ? 0x3F800000u : 0u);
  }
}

// ---------------- bf16 MFMA GEMM: C(MxN) = A(MxK) @ BT(NxK)^T ----------------
template<int MODE>
__global__ __launch_bounds__(256) void gemm_bt(
    const unsigned short* __restrict__ A, int lda,
    const unsigned short* __restrict__ BT, int ldb,
    int K, int nstore,
    float* __restrict__ outF, unsigned short* __restrict__ outB, int ldc,
    const float* __restrict__ bias, const float* __restrict__ rowscale){
  __shared__ unsigned short Asm[64*40];
  __shared__ unsigned short Bsm[128*40];
  const int t = threadIdx.x;
  const int lane = t & 63, wid = t >> 6;
  const int wm = wid >> 1, wn = wid & 1;
  const int row0 = blockIdx.x * 64, col0 = blockIdx.y * 128;
  f32x4 acc[2][4];
  #pragma unroll
  for (int a = 0; a < 2; a++)
    #pragma unroll
    for (int b = 0; b < 4; b++){ acc[a][b][0]=0.f; acc[a][b][1]=0.f; acc[a][b][2]=0.f; acc[a][b][3]=0.f; }

  const int ar = t >> 2, as = t & 3;
  const unsigned short* Ap  = A  + (size_t)(row0 + ar)*lda + as*8;
  const unsigned short* Bp0 = BT + (size_t)(col0 + ar)*ldb + as*8;
  const unsigned short* Bp1 = BT + (size_t)(col0 + ar + 64)*ldb + as*8;
  unsigned short* Asd  = &Asm[ar*40 + as*8];
  unsigned short* Bsd0 = &Bsm[ar*40 + as*8];
  unsigned short* Bsd1 = &Bsm[(ar+64)*40 + as*8];

  const int fr = lane & 15, q = lane >> 4;
  const int aoff = (wm*32 + fr)*40 + q*8;
  const int boff = (wn*64 + fr)*40 + q*8;

  for (int k0 = 0; k0 < K; k0 += 32){
    *(u16x8*)Asd  = *(const u16x8*)(Ap  + k0);
    *(u16x8*)Bsd0 = *(const u16x8*)(Bp0 + k0);
    *(u16x8*)Bsd1 = *(const u16x8*)(Bp1 + k0);
    __syncthreads();
    bf16x8 af0 = *(const bf16x8*)&Asm[aoff];
    bf16x8 af1 = *(const bf16x8*)&Asm[aoff + 16*40];
    bf16x8 bfr[4];
    #pragma unroll
    for (int b = 0; b < 4; b++) bfr[b] = *(const bf16x8*)&Bsm[boff + b*16*40];
    #pragma unroll
    for (int b = 0; b < 4; b++){
      acc[0][b] = __builtin_amdgcn_mfma_f32_16x16x32_bf16(af0, bfr[b], acc[0][b], 0, 0, 0);
      acc[1][b] = __builtin_amdgcn_mfma_f32_16x16x32_bf16(af1, bfr[b], acc[1][b], 0, 0, 0);
    }
    __syncthreads();
  }
  #pragma unroll
  for (int a = 0; a < 2; a++){
    const int grow0 = row0 + wm*32 + a*16 + q*4;
    #pragma unroll
    for (int b = 0; b < 4; b++){
      const int gcol = col0 + wn*64 + b*16 + fr;
      if (gcol < nstore){
        #pragma unroll
        for (int r = 0; r < 4; r++){
          const int grow = grow0 + r;
          float v = acc[a][b][r];
          if (MODE == 0){ v *= rowscale[grow]; outB[(size_t)grow*ldc + gcol] = f2b(v); }
          if (MODE == 1){ v += bias[gcol];     outB[(size_t)grow*ldc + gcol] = f2b(v); }
          if (MODE == 2){ v += bias[gcol];     outF[(size_t)grow*ldc + gcol] = v; }
        }
      }
    }
  }
}

// ---------------- cosine branch ----------------
__global__ __launch_bounds__(256) void k_cos(const unsigned short* __restrict__ nx,
    const unsigned short* __restrict__ xb,
    const int* __restrict__ off_out, const int* __restrict__ csr_out,
    unsigned short* __restrict__ cosf){
  __shared__ float simsb[4][256];
  int wid = threadIdx.x >> 6, lane = threadIdx.x & 63;
  int node = blockIdx.x*4 + wid;
  float own[8];
  { u16x8 o = *(const u16x8*)(nx + (size_t)node*NC + lane*8);
    #pragma unroll
    for (int j=0;j<8;j++) own[j] = b2f(o[j]); }
  int beg = off_out[node], end = off_out[node+1], deg = end - beg;
  float m = -3.0e38f;
  for (int e = 0; e < deg; ++e){
    int d = csr_out[beg+e];
    u16x8 nb = *(const u16x8*)(nx + (size_t)d*NC + lane*8);
    float sp = 0.f;
    #pragma unroll
    for (int j=0;j<8;j++) sp += own[j]*b2f(nb[j]);
    float s = wredsum(sp);
    if (e < 256 && lane == 0) simsb[wid][e] = s;
    m = fmaxf(m, s);
  }
  float den = 0.f, acc[8] = {0,0,0,0,0,0,0,0};
  for (int e = 0; e < deg; ++e){
    int d = csr_out[beg+e];
    float s;
    if (e < 256) s = simsb[wid][e];
    else {
      u16x8 nb = *(const u16x8*)(nx + (size_t)d*NC + lane*8);
      float sp = 0.f;
      #pragma unroll
      for (int j=0;j<8;j++) sp += own[j]*b2f(nb[j]);
      s = wredsum(sp);
    }
    float w = expf(s - m);
    den += w;
    u16x8 xv = *(const u16x8*)(xb + (size_t)d*NC + lane*8);
    #pragma unroll
    for (int j=0;j<8;j++) acc[j] += w * b2f(xv[j]);
  }
  u16x8 o;
  if (deg > 0){
    float r = 1.0f/den;
    #pragma unroll
    for (int j=0;j<8;j++) o[j] = f2b(acc[j]*r);
  } else {
    o = *(const u16x8*)(xb + (size_t)node*NC + lane*8);
  }
  *(u16x8*)(cosf + (size_t)node*NC + lane*8) = o;
}

// ---------------- MP aggregation + relu + cut slice (fused) ----------------
__global__ __launch_bounds__(256) void k_aggcut(const unsigned short* __restrict__ he,
    const unsigned short* __restrict__ hc,
    const int* __restrict__ off_in, const int* __restrict__ csr_in,
    const unsigned short* __restrict__ xb, const float* __restrict__ keep,
    unsigned short* __restrict__ comb){
  int wid = threadIdx.x >> 6, lane = threadIdx.x & 63;
  int node = blockIdx.x*4 + wid;
  float ae[8] = {0,0,0,0,0,0,0,0}, ac[8] = {0,0,0,0,0,0,0,0};
  int beg = off_in[node], end = off_in[node+1];
  for (int e = beg; e < end; ++e){
    int j = csr_in[e];
    u16x8 ve = *(const u16x8*)(he + (size_t)j*NC + lane*8);
    u16x8 vc = *(const u16x8*)(hc + (size_t)j*NC + lane*8);
    #pragma unroll
    for (int k=0;k<8;k++){ ae[k] += b2f(ve[k]); ac[k] += b2f(vc[k]); }
  }
  u16x8 oe, oc;
  #pragma unroll
  for (int k=0;k<8;k++){ oe[k] = f2b(fmaxf(ae[k], 0.f)); oc[k] = f2b(fmaxf(ac[k], 0.f)); }
  *(u16x8*)(comb + (size_t)node*2048 + lane*8) = oe;
  *(u16x8*)(comb + (size_t)node*2048 + 1024 + lane*8) = oc;
  u16x8 xv = *(const u16x8*)(xb + (size_t)node*NC + lane*8);
  if (keep[node] == 0.f){
    #pragma unroll
    for (int j=0;j<8;j++) xv[j] = 0;
  }
  *(u16x8*)(comb + (size_t)node*2048 + 512 + lane*8) = xv;
}

__global__ __launch_bounds__(256) void k_lsm(const float* __restrict__ logits, float* __restrict__ out){
  int wid = threadIdx.x >> 6, lane = threadIdx.x & 63;
  int row = blockIdx.x*4 + wid;
  float v = (lane < 40) ? logits[(size_t)row*64 + lane] : -3.0e38f;
  float m = wredmax(v);
  float e = (lane < 40) ? expf(v - m) : 0.f;
  float s = wredsum(e);
  float l = logf(s);
  if (lane < 40) out[(size_t)row*40 + lane] = v - m - l;
}

// ---------------- dominant branch: big fp64 pieces ----------------
__global__ void k_colmean(const float* __restrict__ x, double* __restrict__ meanbuf){
  int c0 = threadIdx.x;
  int r0 = blockIdx.x*128;
  double s0 = 0, s1 = 0;
  for (int r = r0; r < r0+128; ++r){
    s0 += (double)x[(size_t)r*NC + c0];
    s1 += (double)x[(size_t)r*NC + c0 + 256];
  }
  atomicAdd(&meanbuf[c0], s0);
  atomicAdd(&meanbuf[c0+256], s1);
}

__global__ __launch_bounds__(256) void k_cov(const float* __restrict__ x,
    const double* __restrict__ meanbuf, double* __restrict__ Cm){
  __shared__ float sa[16][33];
  __shared__ float sb[16][33];
  const int t = threadIdx.x;
  const int ti = t & 15, tj = t >> 4;
  const int bi = blockIdx.x, bj = blockIdx.y;
  int l0 = t, l1 = t + 256;
  int r0a = l0 >> 5, c0a = l0 & 31;
  int r1a = l1 >> 5, c1a = l1 & 31;
  float ma0 = (float)(meanbuf[bi*32 + c0a] * (1.0/4096.0));
  float ma1 = (float)(meanbuf[bi*32 + c1a] * (1.0/4096.0));
  float mb0 = (float)(meanbuf[bj*32 + c0a] * (1.0/4096.0));
  float mb1 = (float)(meanbuf[bj*32 + c1a] * (1.0/4096.0));
  double a00=0,a01=0,a10=0,a11=0;
  for (int r0 = 0; r0 < NN; r0 += 16){
    sa[r0a][c0a] = x[(size_t)(r0 + r0a)*NC + bi*32 + c0a] - ma0;
    sa[r1a][c1a] = x[(size_t)(r0 + r1a)*NC + bi*32 + c1a] - ma1;
    sb[r0a][c0a] = x[(size_t)(r0 + r0a)*NC + bj*32 + c0a] - mb0;
    sb[r1a][c1a] = x[(size_t)(r0 + r1a)*NC + bj*32 + c1a] - mb1;
    __syncthreads();
    #pragma unroll
    for (int rr = 0; rr < 16; ++rr){
      double av0 = (double)sa[rr][ti], av1 = (double)sa[rr][ti+16];
      double bv0 = (double)sb[rr][tj], bv1 = (double)sb[rr][tj+16];
      a00 += av0*bv0; a01 += av0*bv1; a10 += av1*bv0; a11 += av1*bv1;
    }
    __syncthreads();
  }
  Cm[(size_t)(bi*32+ti)*512 + bj*32+tj]       = a00;
  Cm[(size_t)(bi*32+ti)*512 + bj*32+tj+16]    = a01;
  Cm[(size_t)(bi*32+ti+16)*512 + bj*32+tj]    = a10;
  Cm[(size_t)(bi*32+ti+16)*512 + bj*32+tj+16] = a11;
}

__global__ __launch_bounds__(256) void k_mm64(const double* __restrict__ A,
    const double* __restrict__ B, double* __restrict__ C){
  __shared__ double sa[32][17];
  __shared__ double sb[16][33];
  const int t = threadIdx.x;
  const int ti = t & 15, tj = t >> 4;
  const int bi = blockIdx.x, bj = blockIdx.y;
  double a00=0,a01=0,a10=0,a11=0;
  for (int k0 = 0; k0 < 512; k0 += 16){
    { int ii = t >> 4, kk = t & 15;
      sa[ii][kk] = A[(size_t)(bi*32+ii)*512 + k0+kk];
      int ii2 = (t+256) >> 4, kk2 = (t+256) & 15;
      sa[ii2][kk2] = A[(size_t)(bi*32+ii2)*512 + k0+kk2];
      int kk3 = t >> 5, jj3 = t & 31;
      sb[kk3][jj3] = B[(size_t)(k0+kk3)*512 + bj*32+jj3];
      int kk4 = (t+256) >> 5, jj4 = (t+256) & 31;
      sb[kk4][jj4] = B[(size_t)(k0+kk4)*512 + bj*32+jj4];
    }
    __syncthreads();
    #pragma unroll
    for (int kk = 0; kk < 16; ++kk){
      double av0 = sa[ti][kk], av1 = sa[ti+16][kk];
      double bv0 = sb[kk][tj], bv1 = sb[kk][tj+16];
      a00 += av0*bv0; a01 += av0*bv1; a10 += av1*bv0; a11 += av1*bv1;
    }
    __syncthreads();
  }
  C[(size_t)(bi*32+ti)*512 + bj*32+tj]       = a00;
  C[(size_t)(bi*32+ti)*512 + bj*32+tj+16]    = a01;
  C[(size_t)(bi*32+ti+16)*512 + bj*32+tj]    = a10;
  C[(size_t)(bi*32+ti+16)*512 + bj*32+tj+16] = a11;
}

// ---------------- cooperative fused tail ----------------
union TailSmem {
  double red[256];
  double L[32][33];
  struct {
    double G[32][33], H[32][33], Q[32][33];
    double pcs[16], pss[16];
    int pp[16], pq[16], map[32], idx[10];
    double eig[32];
  } jac;
  struct {
    float cs[7][10];
    float fs[256][10];
    unsigned char labs[256];
    float sums[77];
  } km;
  struct {
    unsigned u[4096];
    int redc[4];
  } med;
};

__device__ __forceinline__ void matv_step(const double* __restrict__ M,
    const double* __restrict__ Vin, double* __restrict__ Vout, double scale, int gid){
  int r = gid >> 5, c = gid & 31;
  const double* Mr = M + (size_t)r*512;
  double s0=0,s1=0,s2=0,s3=0;
  for (int k = 0; k < 512; k += 4){
    s0 += Mr[k]   * Vin[(size_t)k*32 + c];
    s1 += Mr[k+1] * Vin[(size_t)(k+1)*32 + c];
    s2 += Mr[k+2] * Vin[(size_t)(k+2)*32 + c];
    s3 += Mr[k+3] * Vin[(size_t)(k+3)*32 + c];
  }
  Vout[gid] = ((s0+s1)+(s2+s3))*scale;
}

__global__ __launch_bounds__(256) void k_tail(
    const double* __restrict__ Cm, const double* __restrict__ C16m, const double* __restrict__ C64m,
    double* __restrict__ Va, double* __restrict__ Vb, double* __restrict__ Yb, double* __restrict__ Gm,
    const float* __restrict__ x, const double* __restrict__ meanbuf, float* __restrict__ Pm,
    float* __restrict__ feats, float* __restrict__ part2, float* __restrict__ distb,
    float* __restrict__ keep){
  cg::grid_group grid = cg::this_grid();
  __shared__ TailSmem sm;
  __shared__ double s_scal0, s_scal1;
  const int t = threadIdx.x;
  const int b = blockIdx.x;
  const int gid = b*256 + t;

  // S0: per-block redundant scale factors (exact: max is order-free)
  {
    double m0 = -1e300, m1 = -1e300;
    for (int i = t; i < 512; i += 256){
      m0 = fmax(m0, C16m[(size_t)i*512 + i]);
      m1 = fmax(m1, C64m[(size_t)i*512 + i]);
    }
    sm.red[t] = m0; __syncthreads();
    for (int o = 128; o; o >>= 1){ if (t < o) sm.red[t] = fmax(sm.red[t], sm.red[t+o]); __syncthreads(); }
    if (t == 0) s_scal0 = 1.0 / fmax(sm.red[0], 1e-300);
    __syncthreads();
    sm.red[t] = m1; __syncthreads();
    for (int o = 128; o; o >>= 1){ if (t < o) sm.red[t] = fmax(sm.red[t], sm.red[t+o]); __syncthreads(); }
    if (t == 0) s_scal1 = 1.0 / fmax(sm.red[0], 1e-300);
    __syncthreads();
  }

  // S1: init V0 (same hash/mapping as before)
  {
    unsigned h = (unsigned)gid * 2654435761u + 12345u;
    h ^= h >> 13; h *= 2246822519u; h ^= h >> 16;
    Va[gid] = ((double)(h & 0xffffu) / 32768.0) - 1.0;
  }
  grid.sync();

  // S2: 2 rounds of C^80 = C^64 * C^16 + Cholesky-QR
  for (int it = 0; it < 2; ++it){
    matv_step(C64m, Va, Vb, s_scal1, gid);
    grid.sync();
    matv_step(C16m, Vb, Va, s_scal0, gid);
    grid.sync();
    // Gram: 16 entries per block, serial dot (same order as before)
    if (t < 16){
      int e = b*16 + t; int i = e >> 5, j = e & 31;
      double s = 0;
      for (int k = 0; k < 512; ++k) s += Va[(size_t)k*32+i]*Va[(size_t)k*32+j];
      Gm[e] = s;
    }
    grid.sync();
    // Cholesky redundant per block; trsm rows b*8..b*8+7
    {
      for (int l = t; l < 1024; l += 256){ int i = l >> 5, j = l & 31; sm.L[i][j] = Gm[l]; }
      __syncthreads();
      for (int k = 0; k < 32; ++k){
        if (t == 0) sm.L[k][k] = sqrt(fmax(sm.L[k][k], 1e-300));
        __syncthreads();
        if (t > k && t < 32) sm.L[t][k] /= sm.L[k][k];
        __syncthreads();
        for (int l = t; l < 1024; l += 256){
          int i = l >> 5, j = l & 31;
          if (i > k && j > k && j <= i) sm.L[i][j] -= sm.L[i][k]*sm.L[j][k];
        }
        __syncthreads();
      }
      if (t < 8){
        int r = b*8 + t;
        double v[32];
        #pragma unroll
        for (int jj = 0; jj < 32; ++jj) v[jj] = Va[(size_t)r*32 + jj];
        #pragma unroll
        for (int jj = 0; jj < 32; ++jj){
          double s = v[jj];
          #pragma unroll
          for (int ii = 0; ii < 32; ++ii) if (ii < jj) s -= sm.L[jj][ii]*v[ii];
          v[jj] = s / sm.L[jj][jj];
        }
        #pragma unroll
        for (int jj = 0; jj < 32; ++jj) Va[(size_t)r*32 + jj] = v[jj];
      }
      __syncthreads();
    }
    grid.sync();
  }

  // S3: Yb = Cm * Va (scale 1.0 = identity)
  matv_step(Cm, Va, Yb, 1.0, gid);
  grid.sync();

  // S4: G = Va^T Yb (16 entries/block, serial dot)
  if (t < 16){
    int e = b*16 + t; int i = e >> 5, j = e & 31;
    double s = 0;
    for (int k = 0; k < 512; ++k) s += Va[(size_t)k*32+i]*Yb[(size_t)k*32+j];
    Gm[e] = s;
  }
  grid.sync();

  // S5: Jacobi (block 0 only, 6 sweeps, 4-wave version)
  if (b == 0){
    for (int l = t; l < 1024; l += 256){
      int i = l >> 5, j = l & 31;
      sm.jac.G[i][j] = 0.5*(Gm[i*32+j] + Gm[j*32+i]);
      sm.jac.Q[i][j] = (i == j) ? 1.0 : 0.0;
    }
    __syncthreads();
    for (int sweep = 0; sweep < 6; ++sweep)
    for (int r = 0; r < 31; ++r){
      if (t < 16){
        int u = (t == 0) ? 0 : ((r + t - 1) % 31) + 1;
        int v = ((r + 30 - t) % 31) + 1;
        int p_ = u < v ? u : v, q_ = u < v ? v : u;
        double app = sm.jac.G[p_][p_], aqq = sm.jac.G[q_][q_], apq = sm.jac.G[p_][q_];
        double c, s;
        if (fabs(apq) < 1e-280){ c = 1.0; s = 0.0; }
        else {
          double tau = (aqq - app)/(2.0*apq);
          double tt = (tau >= 0 ? 1.0 : -1.0)/(fabs(tau) + sqrt(1.0 + tau*tau));
          c = 1.0/sqrt(1.0 + tt*tt); s = tt*c;
        }
        sm.jac.pcs[t] = c; sm.jac.pss[t] = s; sm.jac.pp[t] = p_; sm.jac.pq[t] = q_;
        sm.jac.map[p_] = t; sm.jac.map[q_] = t | 32;
      }
      __syncthreads();
      for (int l = t; l < 1024; l += 256){
        int i = l >> 5, j = l & 31;
        int mi = sm.jac.map[i], k = mi & 31;
        double c = sm.jac.pcs[k], s = sm.jac.pss[k];
        double gp = sm.jac.G[sm.jac.pp[k]][j], gq = sm.jac.G[sm.jac.pq[k]][j];
        sm.jac.H[i][j] = (mi & 32) ? (s*gp + c*gq) : (c*gp - s*gq);
      }
      __syncthreads();
      for (int l = t; l < 512; l += 256){
        int i = l >> 4, k = l & 15;
        double c = sm.jac.pcs[k], s = sm.jac.pss[k];
        int p_ = sm.jac.pp[k], q_ = sm.jac.pq[k];
        double hp = sm.jac.H[i][p_], hq = sm.jac.H[i][q_];
        sm.jac.G[i][p_] = c*hp - s*hq; sm.jac.G[i][q_] = s*hp + c*hq;
        double qp = sm.jac.Q[i][p_], qq = sm.jac.Q[i][q_];
        sm.jac.Q[i][p_] = c*qp - s*qq; sm.jac.Q[i][q_] = s*qp + c*qq;
      }
      __syncthreads();
    }
    if (t == 0){
      for (int i2 = 0; i2 < 32; ++i2) sm.jac.eig[i2] = sm.jac.G[i2][i2];
      unsigned used = 0;
      for (int k = 0; k < 10; ++k){
        int best = 0; double bv = -1e300;
        for (int i2 = 0; i2 < 32; ++i2)
          if (!((used >> i2) & 1u) && sm.jac.eig[i2] > bv){ bv = sm.jac.eig[i2]; best = i2; }
        used |= 1u << best; sm.jac.idx[k] = best;
      }
    }
    __syncthreads();
    for (int l = t; l < 5120; l += 256){
      int k = l/10, j = l%10;
      int c = sm.jac.idx[j];
      double s2 = 0;
      for (int m = 0; m < 32; ++m) s2 += Va[(size_t)k*32+m]*sm.jac.Q[m][c];
      Pm[k*10+j] = (float)s2;
    }
  }
  grid.sync();

  // S6: feats = xc @ P  (grid-stride, same per-(n,j) serial loop)
  for (int id = gid; id < 65536; id += 16384){
    int n = id >> 4, j = id & 15;
    if (j < 10){
      float s = 0;
      for (int c2 = 0; c2 < 512; ++c2)
        s += (x[(size_t)n*512+c2] - (float)(meanbuf[c2]*(1.0/4096.0))) * Pm[c2*10+j];
      feats[n*10+j] = s;
    }
  }
  grid.sync();

  // S7: kmeans — 16 blocks own 256 points each; centroid update redundant per block
  if (t < 70) sm.km.cs[t/10][t%10] = feats[t];
  if (b < 16){
    int base = b*256;
    for (int i = t; i < 2560; i += 256) sm.km.fs[i/10][i%10] = feats[base*10 + i];
  }
  __syncthreads();
  for (int iter = 0; iter < 10; ++iter){
    float* pbuf = part2 + (size_t)(iter & 1)*16*77;
    if (b < 16){
      float f[10];
      #pragma unroll
      for (int d = 0; d < 10; ++d) f[d] = sm.km.fs[t][d];
      int best = 0; float bd = 3.0e38f;
      for (int k = 0; k < 7; ++k){
        float s = 0;
        #pragma unroll
        for (int d = 0; d < 10; ++d){ float df = f[d]-sm.km.cs[k][d]; s += df*df; }
        if (s < bd){ bd = s; best = k; }
      }
      sm.km.labs[t] = (unsigned char)best;
      __syncthreads();
      if (t < 77){
        float acc = 0;
        if (t < 70){
          int k = t/10, d = t%10;
          for (int nn = 0; nn < 256; ++nn) if (sm.km.labs[nn] == k) acc += sm.km.fs[nn][d];
        } else {
          int k = t - 70;
          for (int nn = 0; nn < 256; ++nn) if (sm.km.labs[nn] == k) acc += 1.f;
        }
        pbuf[b*77 + t] = acc;
      }
    }
    grid.sync();
    if (t < 77){
      float s = 0;
      for (int bb = 0; bb < 16; ++bb) s += pbuf[bb*77 + t];
      sm.km.sums[t] = s;
    }
    __syncthreads();
    if (t < 70){
      float cnt = sm.km.sums[70 + t/10];
      if (cnt > 0.f) sm.km.cs[t/10][t%10] = sm.km.sums[t] / fmaxf(cnt, 1.f);
    }
    __syncthreads();
  }
  // final distances
  if (b < 16){
    float f[10];
    #pragma unroll
    for (int d = 0; d < 10; ++d) f[d] = sm.km.fs[t][d];
    float bd = 3.0e38f;
    for (int k = 0; k < 7; ++k){
      float s = 0;
      #pragma unroll
      for (int d = 0; d < 10; ++d){ float df = f[d]-sm.km.cs[k][d]; s += df*df; }
      bd = fminf(bd, s);
    }
    distb[b*256 + t] = sqrtf(bd);
  }
  grid.sync();

  // S8: exact median (radix select) + keep, block 0 only
  if (b == 0){
    for (int i = t; i < 4096; i += 256) sm.med.u[i] = __float_as_uint(distb[i]);
    __syncthreads();
    unsigned vals[2];
    for (int ri = 0; ri < 2; ++ri){
      int r = 2047 + ri;
      unsigned prefix = 0;
      for (int bit = 31; bit >= 0; --bit){
        unsigned hm = (bit < 31) ? (0xffffffffu << (bit+1)) : 0u;
        int c = 0;
        for (int i = t; i < 4096; i += 256){
          unsigned e = sm.med.u[i];
          if ((e & hm) == prefix && !((e >> bit) & 1u)) c++;
        }
        #pragma unroll
        for (int o = 32; o; o >>= 1) c += __shfl_xor(c, o, 64);
        if ((t & 63) == 0) sm.med.redc[t >> 6] = c;
        __syncthreads();
        int tot = sm.med.redc[0] + sm.med.redc[1] + sm.med.redc[2] + sm.med.redc[3];
        if (r >= tot){ prefix |= (1u << bit); r -= tot; }
        __syncthreads();
      }
      vals[ri] = prefix;
    }
    float med = 0.5f*(__uint_as_float(vals[0]) + __uint_as_float(vals[1]));
    for (int i = t; i < 4096; i += 256) keep[i] = (distb[i] <= med) ? 1.f : 0.f;
  }
}

// ---------------- launch ----------------
extern "C" void kernel_launch(void* const* d_in, const int* in_sizes, int n_in,
                              void* d_out, int out_size, void* d_ws, size_t ws_size,
                              hipStream_t stream){
  const float* x      = (const float*)d_in[0];
  const float* W_ego  = (const float*)d_in[1];
  const float* b_ego  = (const float*)d_in[2];
  const float* W_cos  = (const float*)d_in[3];
  const float* b_cos  = (const float*)d_in[4];
  const float* W_glob = (const float*)d_in[5];
  const float* b_glob = (const float*)d_in[6];
  const float* W_fc   = (const float*)d_in[7];
  const float* b_fc   = (const float*)d_in[8];
  const int*   ei     = (const int*)d_in[9];
  const int* src = ei;
  const int* dst = ei + NE;
  float* out = (float*)d_out;

  char* p = (char*)d_ws;
  auto alloc = [&](size_t n) -> char* { char* r = p; p += (n + 255) & ~(size_t)255; return r; };

  unsigned long long* B1 = (unsigned long long*)alloc((size_t)NN*64*8);
  unsigned short* Mf     = (unsigned short*)alloc((size_t)NN*NN*2);
  unsigned short* x_bf   = (unsigned short*)alloc((size_t)NN*NC*2);
  unsigned short* xT_bf  = (unsigned short*)alloc((size_t)NN*NC*2);
  unsigned short* nx_bf  = (unsigned short*)alloc((size_t)NN*NC*2);
  unsigned short* egof   = (unsigned short*)alloc((size_t)NN*NC*2);
  unsigned short* cosf   = (unsigned short*)alloc((size_t)NN*NC*2);
  unsigned short* h_ego  = (unsigned short*)alloc((size_t)NN*NC*2);
  unsigned short* h_cos  = (unsigned short*)alloc((size_t)NN*NC*2);
  unsigned short* WegoT  = (unsigned short*)alloc((size_t)512*512*2);
  unsigned short* WcosT  = (unsigned short*)alloc((size_t)512*512*2);
  unsigned short* WglobT = (unsigned short*)alloc((size_t)512*512*2);
  unsigned short* WfcT   = (unsigned short*)alloc((size_t)128*2048*2);
  unsigned short* comb   = (unsigned short*)alloc((size_t)NN*2048*2);
  float* logits   = (float*)alloc((size_t)NN*64*4);
  float* rowrecip = (float*)alloc((size_t)NN*4);
  float* keep     = (float*)alloc((size_t)NN*4);
  int* cnt_in   = (int*)alloc((size_t)NN*4);
  int* cnt_out  = (int*)alloc((size_t)NN*4);
  int* off_in   = (int*)alloc((size_t)(NN+1)*4);
  int* off_out  = (int*)alloc((size_t)(NN+1)*4);
  int* fill_in  = (int*)alloc((size_t)NN*4);
  int* fill_out = (int*)alloc((size_t)NN*4);
  int* csr_in   = (int*)alloc((size_t)NE*4);
  int* csr_out  = (int*)alloc((size_t)NE*4);
  double* meanbuf = (double*)alloc(512*8);
  double* Cm  = (double*)alloc((size_t)512*512*8);
  double* C2m = (double*)alloc((size_t)512*512*8);
  double* C4m = (double*)alloc((size_t)512*512*8);
  double* C8m = (double*)alloc((size_t)512*512*8);
  double* C16m = (double*)alloc((size_t)512*512*8);
  double* C32m = (double*)alloc((size_t)512*512*8);
  double* C64m = (double*)alloc((size_t)512*512*8);
  double* Va  = (double*)alloc((size_t)512*32*8);
  double* Vb  = (double*)alloc((size_t)512*32*8);
  double* Yb  = (double*)alloc((size_t)512*32*8);
  double* Gm  = (double*)alloc(32*32*8);
  float* Pm    = (float*)alloc((size_t)512*10*4);
  float* feats = (float*)alloc((size_t)NN*10*4);
  float* part  = (float*)alloc((size_t)2*16*77*4);
  float* distb = (float*)alloc((size_t)NN*4);

  hipMemsetAsync(B1, 0, (size_t)NN*64*8, stream);
  hipMemsetAsync(cnt_in, 0, (size_t)NN*4, stream);
  hipMemsetAsync(cnt_out, 0, (size_t)NN*4, stream);
  hipMemsetAsync(meanbuf, 0, 512*8, stream);
  hipMemsetAsync(WfcT, 0, (size_t)128*2048*2, stream);

  // conversions
  k_transconv<<<dim3(8,64), 256, 0, stream>>>(x, NN, NC, xT_bf, NN, x_bf);
  k_transconv3<<<dim3(8,8,3), 256, 0, stream>>>(W_ego, W_cos, W_glob, WegoT, WcosT, WglobT);
  k_transconv<<<dim3(1,32), 256, 0, stream>>>(W_fc, 2048, 40, WfcT, 2048, (unsigned short*)0);
  k_normx<<<1024, 256, 0, stream>>>(x, nx_bf);

  // CSR + bitsets (fused edge pass)
  k_count_b1<<<512, 256, 0, stream>>>(src, dst, cnt_in, cnt_out, B1);
  k_scan<<<1, 1024, 0, stream>>>(cnt_in, cnt_out, off_in, off_out, fill_in, fill_out);
  k_fill<<<512, 256, 0, stream>>>(src, dst, fill_in, fill_out, csr_in, csr_out);
  k_bits2<<<1024, 256, 0, stream>>>(B1, off_in, csr_in, Mf, rowrecip);

  // ego_feats = (Mf @ x) / rowsum
  gemm_bt<0><<<dim3(64,4), 256, 0, stream>>>(Mf, NN, xT_bf, NN, NN, NC,
      (float*)0, egof, NC, (const float*)0, rowrecip);

  // dominant branch: big fp64 pieces
  k_colmean<<<32, 256, 0, stream>>>(x, meanbuf);
  k_cov<<<dim3(16,16), 256, 0, stream>>>(x, meanbuf, Cm);
  k_mm64<<<dim3(16,16), 256, 0, stream>>>(Cm,  Cm,  C2m);
  k_mm64<<<dim3(16,16), 256, 0, stream>>>(C2m, C2m, C4m);
  k_mm64<<<dim3(16,16), 256, 0, stream>>>(C4m, C4m, C8m);
  k_mm64<<<dim3(16,16), 256, 0, stream>>>(C8m, C8m, C16m);
  k_mm64<<<dim3(16,16), 256, 0, stream>>>(C16m, C16m, C32m);
  k_mm64<<<dim3(16,16), 256, 0, stream>>>(C32m, C32m, C64m);

  // fused cooperative tail: subspace iter + Rayleigh-Ritz + Jacobi + feats + kmeans + median
  {
    void* args[] = { (void*)&Cm, (void*)&C16m, (void*)&C64m, (void*)&Va, (void*)&Vb,
                     (void*)&Yb, (void*)&Gm, (void*)&x, (void*)&meanbuf, (void*)&Pm,
                     (void*)&feats, (void*)&part, (void*)&distb, (void*)&keep };
    hipLaunchCooperativeKernel((void*)k_tail, dim3(64), dim3(256), args, 0, stream);
  }

  // cosine branch
  k_cos<<<1024, 256, 0, stream>>>(nx_bf, x_bf, off_out, csr_out, cosf);

  // encoders
  gemm_bt<1><<<dim3(64,4), 256, 0, stream>>>(egof, NC, WegoT, 512, 512, NC,
      (float*)0, h_ego, NC, b_ego, (const float*)0);
  gemm_bt<1><<<dim3(64,4), 256, 0, stream>>>(cosf, NC, WcosT, 512, 512, NC,
      (float*)0, h_cos, NC, b_cos, (const float*)0);
  gemm_bt<1><<<dim3(64,4), 256, 0, stream>>>(x_bf, NC, WglobT, 512, 512, NC,
      (float*)0, comb + 1536, 2048, b_glob, (const float*)0);

  // aggregation + cut into combined (fused)
  k_aggcut<<<1024, 256, 0, stream>>>(h_ego, h_cos, off_in, csr_in, x_bf, keep, comb);

  // head + log_softmax
  gemm_bt<2><<<dim3(64,1), 256, 0, stream>>>(comb, 2048, WfcT, 2048, 2048, 40,
      logits, (unsigned short*)0, 64, b_fc, (const float*)0);
  k_lsm<<<1024, 256, 0, stream>>>(logits, out);
}

// Round 11
// 1761.842 us; speedup vs baseline: 1.0373x; 1.0373x over previous
//
#include <hip/hip_runtime.h>
#include <hip/hip_cooperative_groups.h>
#include <math.h>

namespace cg = cooperative_groups;

#define NN 4096
#define NC 512
#define NE 131072

typedef __bf16 bf16x8 __attribute__((ext_vector_type(8)));
typedef float f32x4 __attribute__((ext_vector_type(4)));
typedef unsigned short u16x8 __attribute__((ext_vector_type(8)));

__device__ __forceinline__ unsigned short f2b(float f){
  unsigned u = __float_as_uint(f);
  u += 0x7fffu + ((u >> 16) & 1u);
  return (unsigned short)(u >> 16);
}
__device__ __forceinline__ float b2f(unsigned short h){
  return __uint_as_float(((unsigned)h) << 16);
}
__device__ __forceinline__ float wredsum(float v){
  #pragma unroll
  for (int o = 32; o; o >>= 1) v += __shfl_xor(v, o, 64);
  return v;
}
__device__ __forceinline__ float wredmax(float v){
  #pragma unroll
  for (int o = 32; o; o >>= 1) v = fmaxf(v, __shfl_xor(v, o, 64));
  return v;
}

// ---------------- conversions / transpose ----------------
__global__ __launch_bounds__(256) void k_transconv(const float* __restrict__ src, int R, int C,
    unsigned short* __restrict__ dstT, int ldT, unsigned short* __restrict__ dstD){
  __shared__ unsigned short tile[64][65];
  int bc = blockIdx.x * 64, br = blockIdx.y * 64;
  int t = threadIdx.x, lc = t & 63, lr4 = t >> 6;
  for (int j = 0; j < 16; ++j){
    int r = br + lr4*16 + j, c = bc + lc;
    float v = (r < R && c < C) ? src[(size_t)r*C + c] : 0.f;
    unsigned short b = f2b(v);
    tile[lr4*16+j][lc] = b;
    if (dstD && r < R && c < C) dstD[(size_t)r*C + c] = b;
  }
  __syncthreads();
  for (int j = 0; j < 16; ++j){
    int cc = bc + lr4*16 + j, rr = br + lc;
    if (cc < C && rr < R) dstT[(size_t)cc*ldT + rr] = tile[lc][lr4*16+j];
  }
}

// three 512x512 weight transposes in one launch (blockIdx.z selects matrix)
__global__ __launch_bounds__(256) void k_transconv3(const float* __restrict__ A,
    const float* __restrict__ B, const float* __restrict__ C,
    unsigned short* __restrict__ TA, unsigned short* __restrict__ TB, unsigned short* __restrict__ TC){
  __shared__ unsigned short tile[64][65];
  const float* src = (blockIdx.z == 0) ? A : ((blockIdx.z == 1) ? B : C);
  unsigned short* dstT = (blockIdx.z == 0) ? TA : ((blockIdx.z == 1) ? TB : TC);
  int bc = blockIdx.x * 64, br = blockIdx.y * 64;
  int t = threadIdx.x, lc = t & 63, lr4 = t >> 6;
  for (int j = 0; j < 16; ++j){
    int r = br + lr4*16 + j, c = bc + lc;
    tile[lr4*16+j][lc] = f2b(src[(size_t)r*512 + c]);
  }
  __syncthreads();
  for (int j = 0; j < 16; ++j){
    int cc = bc + lr4*16 + j, rr = br + lc;
    dstT[(size_t)cc*512 + rr] = tile[lc][lr4*16+j];
  }
}

__global__ __launch_bounds__(256) void k_normx(const float* __restrict__ x, unsigned short* __restrict__ nx){
  int wid = threadIdx.x >> 6, lane = threadIdx.x & 63;
  int row = blockIdx.x*4 + wid;
  const float* xr = x + (size_t)row*NC + lane*8;
  float v[8]; float ss = 0.f;
  #pragma unroll
  for (int j=0;j<8;j++){ v[j] = xr[j]; ss += v[j]*v[j]; }
  ss = wredsum(ss);
  float sc = 1.0f / fmaxf(sqrtf(ss), 1e-12f);
  u16x8 o;
  #pragma unroll
  for (int j=0;j<8;j++) o[j] = f2b(v[j]*sc);
  *(u16x8*)(nx + (size_t)row*NC + lane*8) = o;
}

// ---------------- CSR + 1-hop bitset (fused edge pass) ----------------
__global__ void k_count_b1(const int* __restrict__ src, const int* __restrict__ dst,
    int* cin, int* cout, unsigned long long* B1){
  int e = blockIdx.x*256 + threadIdx.x;
  if (e < NE){
    int s = src[e], d = dst[e];
    atomicAdd(&cout[s], 1);
    atomicAdd(&cin[d], 1);
    atomicOr(&B1[(size_t)d*64 + (s>>6)], 1ull << (s & 63));
  }
}
__global__ __launch_bounds__(1024) void k_scan(const int* __restrict__ cnt0, const int* __restrict__ cnt1,
    int* off0, int* off1, int* fill0, int* fill1){
  __shared__ int s[1024];
  int t = threadIdx.x;
  for (int arr = 0; arr < 2; ++arr){
    const int* cnt = arr ? cnt1 : cnt0;
    int* off = arr ? off1 : off0;
    int* fill = arr ? fill1 : fill0;
    int a0 = cnt[t*4], a1 = cnt[t*4+1], a2 = cnt[t*4+2], a3 = cnt[t*4+3];
    int ts = a0+a1+a2+a3;
    s[t] = ts; __syncthreads();
    for (int o = 1; o < 1024; o <<= 1){
      int v = (t >= o) ? s[t-o] : 0; __syncthreads();
      s[t] += v; __syncthreads();
    }
    int ex = s[t] - ts;
    off[t*4] = ex; off[t*4+1] = ex+a0; off[t*4+2] = ex+a0+a1; off[t*4+3] = ex+a0+a1+a2;
    fill[t*4] = ex; fill[t*4+1] = ex+a0; fill[t*4+2] = ex+a0+a1; fill[t*4+3] = ex+a0+a1+a2;
    if (t == 1023) off[4096] = s[1023];
    __syncthreads();
  }
}
__global__ void k_fill(const int* __restrict__ src, const int* __restrict__ dst,
    int* fin, int* fout, int* csr_in, int* csr_out){
  int e = blockIdx.x*256 + threadIdx.x;
  if (e < NE){
    int s = src[e], d = dst[e];
    int pi = atomicAdd(&fin[d], 1);  csr_in[pi] = s;
    int po = atomicAdd(&fout[s], 1); csr_out[po] = d;
  }
}

// ---------------- ego 2-hop bitsets -> dense bf16 Mf ----------------
__global__ __launch_bounds__(256) void k_bits2(const unsigned long long* __restrict__ B1,
    const int* __restrict__ off_in, const int* __restrict__ csr_in,
    unsigned short* __restrict__ Mf, float* __restrict__ rowrecip){
  int wid = threadIdx.x >> 6, lane = threadIdx.x & 63;
  int node = blockIdx.x*4 + wid;
  unsigned long long bits = B1[(size_t)node*64 + lane];
  if (lane == (node >> 6)) bits |= 1ull << (node & 63);
  int beg = off_in[node], end = off_in[node+1];
  for (int e = beg; e < end; ++e){
    int j = csr_in[e];
    bits |= B1[(size_t)j*64 + lane];
  }
  int pc = __popcll(bits);
  #pragma unroll
  for (int o = 32; o; o >>= 1) pc += __shfl_xor(pc, o, 64);
  if (lane == 0) rowrecip[node] = 1.0f / (float)pc;
  unsigned lo = (unsigned)(bits & 0xffffffffull), hi = (unsigned)(bits >> 32);
  unsigned int* Mrow = (unsigned int*)(Mf + (size_t)node*NN);
  for (int k = 0; k < 32; ++k){
    int srcl = 2*k + (lane >> 5);
    unsigned wlo = (unsigned)__shfl((int)lo, srcl, 64);
    unsigned whi = (unsigned)__shfl((int)hi, srcl, 64);
    unsigned long long w2 = ((unsigned long long)whi << 32) | wlo;
    int sh = (lane & 31) * 2;
    unsigned v = (unsigned)((w2 >> sh) & 3ull);
    Mrow[k*64 + lane] = ((v & 1u) ? 0x3F80u : 0u) | ((v & 2u) ? 0x3F800000u : 0u);
  }
}

// ---------------- bf16 MFMA GEMM: C(MxN) = A(MxK) @ BT(NxK)^T ----------------
template<int MODE>
__global__ __launch_bounds__(256) void gemm_bt(
    const unsigned short* __restrict__ A, int lda,
    const unsigned short* __restrict__ BT, int ldb,
    int K, int nstore,
    float* __restrict__ outF, unsigned short* __restrict__ outB, int ldc,
    const float* __restrict__ bias, const float* __restrict__ rowscale){
  __shared__ unsigned short Asm[64*40];
  __shared__ unsigned short Bsm[128*40];
  const int t = threadIdx.x;
  const int lane = t & 63, wid = t >> 6;
  const int wm = wid >> 1, wn = wid & 1;
  const int row0 = blockIdx.x * 64, col0 = blockIdx.y * 128;
  f32x4 acc[2][4];
  #pragma unroll
  for (int a = 0; a < 2; a++)
    #pragma unroll
    for (int b = 0; b < 4; b++){ acc[a][b][0]=0.f; acc[a][b][1]=0.f; acc[a][b][2]=0.f; acc[a][b][3]=0.f; }

  const int ar = t >> 2, as = t & 3;
  const unsigned short* Ap  = A  + (size_t)(row0 + ar)*lda + as*8;
  const unsigned short* Bp0 = BT + (size_t)(col0 + ar)*ldb + as*8;
  const unsigned short* Bp1 = BT + (size_t)(col0 + ar + 64)*ldb + as*8;
  unsigned short* Asd  = &Asm[ar*40 + as*8];
  unsigned short* Bsd0 = &Bsm[ar*40 + as*8];
  unsigned short* Bsd1 = &Bsm[(ar+64)*40 + as*8];

  const int fr = lane & 15, q = lane >> 4;
  const int aoff = (wm*32 + fr)*40 + q*8;
  const int boff = (wn*64 + fr)*40 + q*8;

  for (int k0 = 0; k0 < K; k0 += 32){
    *(u16x8*)Asd  = *(const u16x8*)(Ap  + k0);
    *(u16x8*)Bsd0 = *(const u16x8*)(Bp0 + k0);
    *(u16x8*)Bsd1 = *(const u16x8*)(Bp1 + k0);
    __syncthreads();
    bf16x8 af0 = *(const bf16x8*)&Asm[aoff];
    bf16x8 af1 = *(const bf16x8*)&Asm[aoff + 16*40];
    bf16x8 bfr[4];
    #pragma unroll
    for (int b = 0; b < 4; b++) bfr[b] = *(const bf16x8*)&Bsm[boff + b*16*40];
    #pragma unroll
    for (int b = 0; b < 4; b++){
      acc[0][b] = __builtin_amdgcn_mfma_f32_16x16x32_bf16(af0, bfr[b], acc[0][b], 0, 0, 0);
      acc[1][b] = __builtin_amdgcn_mfma_f32_16x16x32_bf16(af1, bfr[b], acc[1][b], 0, 0, 0);
    }
    __syncthreads();
  }
  #pragma unroll
  for (int a = 0; a < 2; a++){
    const int grow0 = row0 + wm*32 + a*16 + q*4;
    #pragma unroll
    for (int b = 0; b < 4; b++){
      const int gcol = col0 + wn*64 + b*16 + fr;
      if (gcol < nstore){
        #pragma unroll
        for (int r = 0; r < 4; r++){
          const int grow = grow0 + r;
          float v = acc[a][b][r];
          if (MODE == 0){ v *= rowscale[grow]; outB[(size_t)grow*ldc + gcol] = f2b(v); }
          if (MODE == 1){ v += bias[gcol];     outB[(size_t)grow*ldc + gcol] = f2b(v); }
          if (MODE == 2){ v += bias[gcol];     outF[(size_t)grow*ldc + gcol] = v; }
        }
      }
    }
  }
}

// three encoder GEMMs (M=4096,N=512,K=512, MODE1 semantics) in one launch, z selects
__global__ __launch_bounds__(256) void gemm_bt3(
    const unsigned short* __restrict__ A0, const unsigned short* __restrict__ A1, const unsigned short* __restrict__ A2,
    const unsigned short* __restrict__ B0, const unsigned short* __restrict__ B1g, const unsigned short* __restrict__ B2,
    const float* __restrict__ bias0, const float* __restrict__ bias1, const float* __restrict__ bias2,
    unsigned short* __restrict__ o0, unsigned short* __restrict__ o1, unsigned short* __restrict__ o2,
    int ldc2){
  const int z = blockIdx.z;
  const unsigned short* A  = (z == 0) ? A0 : ((z == 1) ? A1 : A2);
  const unsigned short* BT = (z == 0) ? B0 : ((z == 1) ? B1g : B2);
  const float* bias        = (z == 0) ? bias0 : ((z == 1) ? bias1 : bias2);
  unsigned short* outB     = (z == 0) ? o0 : ((z == 1) ? o1 : o2);
  const int ldc = (z == 2) ? ldc2 : 512;

  __shared__ unsigned short Asm[64*40];
  __shared__ unsigned short Bsm[128*40];
  const int t = threadIdx.x;
  const int lane = t & 63, wid = t >> 6;
  const int wm = wid >> 1, wn = wid & 1;
  const int row0 = blockIdx.x * 64, col0 = blockIdx.y * 128;
  f32x4 acc[2][4];
  #pragma unroll
  for (int a = 0; a < 2; a++)
    #pragma unroll
    for (int b = 0; b < 4; b++){ acc[a][b][0]=0.f; acc[a][b][1]=0.f; acc[a][b][2]=0.f; acc[a][b][3]=0.f; }

  const int ar = t >> 2, as = t & 3;
  const unsigned short* Ap  = A  + (size_t)(row0 + ar)*512 + as*8;
  const unsigned short* Bp0 = BT + (size_t)(col0 + ar)*512 + as*8;
  const unsigned short* Bp1 = BT + (size_t)(col0 + ar + 64)*512 + as*8;
  unsigned short* Asd  = &Asm[ar*40 + as*8];
  unsigned short* Bsd0 = &Bsm[ar*40 + as*8];
  unsigned short* Bsd1 = &Bsm[(ar+64)*40 + as*8];

  const int fr = lane & 15, q = lane >> 4;
  const int aoff = (wm*32 + fr)*40 + q*8;
  const int boff = (wn*64 + fr)*40 + q*8;

  for (int k0 = 0; k0 < 512; k0 += 32){
    *(u16x8*)Asd  = *(const u16x8*)(Ap  + k0);
    *(u16x8*)Bsd0 = *(const u16x8*)(Bp0 + k0);
    *(u16x8*)Bsd1 = *(const u16x8*)(Bp1 + k0);
    __syncthreads();
    bf16x8 af0 = *(const bf16x8*)&Asm[aoff];
    bf16x8 af1 = *(const bf16x8*)&Asm[aoff + 16*40];
    bf16x8 bfr[4];
    #pragma unroll
    for (int b = 0; b < 4; b++) bfr[b] = *(const bf16x8*)&Bsm[boff + b*16*40];
    #pragma unroll
    for (int b = 0; b < 4; b++){
      acc[0][b] = __builtin_amdgcn_mfma_f32_16x16x32_bf16(af0, bfr[b], acc[0][b], 0, 0, 0);
      acc[1][b] = __builtin_amdgcn_mfma_f32_16x16x32_bf16(af1, bfr[b], acc[1][b], 0, 0, 0);
    }
    __syncthreads();
  }
  #pragma unroll
  for (int a = 0; a < 2; a++){
    const int grow0 = row0 + wm*32 + a*16 + q*4;
    #pragma unroll
    for (int b = 0; b < 4; b++){
      const int gcol = col0 + wn*64 + b*16 + fr;
      #pragma unroll
      for (int r = 0; r < 4; r++){
        const int grow = grow0 + r;
        float v = acc[a][b][r] + bias[gcol];
        outB[(size_t)grow*ldc + gcol] = f2b(v);
      }
    }
  }
}

// ---------------- cosine branch ----------------
__global__ __launch_bounds__(256) void k_cos(const unsigned short* __restrict__ nx,
    const unsigned short* __restrict__ xb,
    const int* __restrict__ off_out, const int* __restrict__ csr_out,
    unsigned short* __restrict__ cosf){
  __shared__ float simsb[4][256];
  int wid = threadIdx.x >> 6, lane = threadIdx.x & 63;
  int node = blockIdx.x*4 + wid;
  float own[8];
  { u16x8 o = *(const u16x8*)(nx + (size_t)node*NC + lane*8);
    #pragma unroll
    for (int j=0;j<8;j++) own[j] = b2f(o[j]); }
  int beg = off_out[node], end = off_out[node+1], deg = end - beg;
  float m = -3.0e38f;
  for (int e = 0; e < deg; ++e){
    int d = csr_out[beg+e];
    u16x8 nb = *(const u16x8*)(nx + (size_t)d*NC + lane*8);
    float sp = 0.f;
    #pragma unroll
    for (int j=0;j<8;j++) sp += own[j]*b2f(nb[j]);
    float s = wredsum(sp);
    if (e < 256 && lane == 0) simsb[wid][e] = s;
    m = fmaxf(m, s);
  }
  float den = 0.f, acc[8] = {0,0,0,0,0,0,0,0};
  for (int e = 0; e < deg; ++e){
    int d = csr_out[beg+e];
    float s;
    if (e < 256) s = simsb[wid][e];
    else {
      u16x8 nb = *(const u16x8*)(nx + (size_t)d*NC + lane*8);
      float sp = 0.f;
      #pragma unroll
      for (int j=0;j<8;j++) sp += own[j]*b2f(nb[j]);
      s = wredsum(sp);
    }
    float w = expf(s - m);
    den += w;
    u16x8 xv = *(const u16x8*)(xb + (size_t)d*NC + lane*8);
    #pragma unroll
    for (int j=0;j<8;j++) acc[j] += w * b2f(xv[j]);
  }
  u16x8 o;
  if (deg > 0){
    float r = 1.0f/den;
    #pragma unroll
    for (int j=0;j<8;j++) o[j] = f2b(acc[j]*r);
  } else {
    o = *(const u16x8*)(xb + (size_t)node*NC + lane*8);
  }
  *(u16x8*)(cosf + (size_t)node*NC + lane*8) = o;
}

// ---------------- MP aggregation + relu + cut slice (fused) ----------------
__global__ __launch_bounds__(256) void k_aggcut(const unsigned short* __restrict__ he,
    const unsigned short* __restrict__ hc,
    const int* __restrict__ off_in, const int* __restrict__ csr_in,
    const unsigned short* __restrict__ xb, const float* __restrict__ keep,
    unsigned short* __restrict__ comb){
  int wid = threadIdx.x >> 6, lane = threadIdx.x & 63;
  int node = blockIdx.x*4 + wid;
  float ae[8] = {0,0,0,0,0,0,0,0}, ac[8] = {0,0,0,0,0,0,0,0};
  int beg = off_in[node], end = off_in[node+1];
  for (int e = beg; e < end; ++e){
    int j = csr_in[e];
    u16x8 ve = *(const u16x8*)(he + (size_t)j*NC + lane*8);
    u16x8 vc = *(const u16x8*)(hc + (size_t)j*NC + lane*8);
    #pragma unroll
    for (int k=0;k<8;k++){ ae[k] += b2f(ve[k]); ac[k] += b2f(vc[k]); }
  }
  u16x8 oe, oc;
  #pragma unroll
  for (int k=0;k<8;k++){ oe[k] = f2b(fmaxf(ae[k], 0.f)); oc[k] = f2b(fmaxf(ac[k], 0.f)); }
  *(u16x8*)(comb + (size_t)node*2048 + lane*8) = oe;
  *(u16x8*)(comb + (size_t)node*2048 + 1024 + lane*8) = oc;
  u16x8 xv = *(const u16x8*)(xb + (size_t)node*NC + lane*8);
  if (keep[node] == 0.f){
    #pragma unroll
    for (int j=0;j<8;j++) xv[j] = 0;
  }
  *(u16x8*)(comb + (size_t)node*2048 + 512 + lane*8) = xv;
}

__global__ __launch_bounds__(256) void k_lsm(const float* __restrict__ logits, float* __restrict__ out){
  int wid = threadIdx.x >> 6, lane = threadIdx.x & 63;
  int row = blockIdx.x*4 + wid;
  float v = (lane < 40) ? logits[(size_t)row*64 + lane] : -3.0e38f;
  float m = wredmax(v);
  float e = (lane < 40) ? expf(v - m) : 0.f;
  float s = wredsum(e);
  float l = logf(s);
  if (lane < 40) out[(size_t)row*40 + lane] = v - m - l;
}

// ---------------- dominant branch: big fp64 pieces ----------------
__global__ void k_colmean(const float* __restrict__ x, double* __restrict__ meanbuf){
  int c0 = threadIdx.x;
  int r0 = blockIdx.x*128;
  double s0 = 0, s1 = 0;
  for (int r = r0; r < r0+128; ++r){
    s0 += (double)x[(size_t)r*NC + c0];
    s1 += (double)x[(size_t)r*NC + c0 + 256];
  }
  atomicAdd(&meanbuf[c0], s0);
  atomicAdd(&meanbuf[c0+256], s1);
}

// symmetric: compute only bi<=bj blocks, mirror-store (bitwise identical: same
// products, same accumulation order, IEEE multiply commutes)
__global__ __launch_bounds__(256) void k_cov(const float* __restrict__ x,
    const double* __restrict__ meanbuf, double* __restrict__ Cm){
  const int bi = blockIdx.x, bj = blockIdx.y;
  if (bi > bj) return;
  __shared__ float sa[16][33];
  __shared__ float sb[16][33];
  const int t = threadIdx.x;
  const int ti = t & 15, tj = t >> 4;
  int l0 = t, l1 = t + 256;
  int r0a = l0 >> 5, c0a = l0 & 31;
  int r1a = l1 >> 5, c1a = l1 & 31;
  float ma0 = (float)(meanbuf[bi*32 + c0a] * (1.0/4096.0));
  float ma1 = (float)(meanbuf[bi*32 + c1a] * (1.0/4096.0));
  float mb0 = (float)(meanbuf[bj*32 + c0a] * (1.0/4096.0));
  float mb1 = (float)(meanbuf[bj*32 + c1a] * (1.0/4096.0));
  double a00=0,a01=0,a10=0,a11=0;
  for (int r0 = 0; r0 < NN; r0 += 16){
    sa[r0a][c0a] = x[(size_t)(r0 + r0a)*NC + bi*32 + c0a] - ma0;
    sa[r1a][c1a] = x[(size_t)(r0 + r1a)*NC + bi*32 + c1a] - ma1;
    sb[r0a][c0a] = x[(size_t)(r0 + r0a)*NC + bj*32 + c0a] - mb0;
    sb[r1a][c1a] = x[(size_t)(r0 + r1a)*NC + bj*32 + c1a] - mb1;
    __syncthreads();
    #pragma unroll
    for (int rr = 0; rr < 16; ++rr){
      double av0 = (double)sa[rr][ti], av1 = (double)sa[rr][ti+16];
      double bv0 = (double)sb[rr][tj], bv1 = (double)sb[rr][tj+16];
      a00 += av0*bv0; a01 += av0*bv1; a10 += av1*bv0; a11 += av1*bv1;
    }
    __syncthreads();
  }
  const int r0i = bi*32+ti, r1i = bi*32+ti+16, c0j = bj*32+tj, c1j = bj*32+tj+16;
  Cm[(size_t)r0i*512 + c0j] = a00;
  Cm[(size_t)r0i*512 + c1j] = a01;
  Cm[(size_t)r1i*512 + c0j] = a10;
  Cm[(size_t)r1i*512 + c1j] = a11;
  if (bi < bj){
    Cm[(size_t)c0j*512 + r0i] = a00;
    Cm[(size_t)c1j*512 + r0i] = a01;
    Cm[(size_t)c0j*512 + r1i] = a10;
    Cm[(size_t)c1j*512 + r1i] = a11;
  }
}

// symmetric product of a symmetric matrix with itself: triangular + mirror (bitwise safe)
__global__ __launch_bounds__(256) void k_mm64(const double* __restrict__ A,
    const double* __restrict__ B, double* __restrict__ C){
  const int bi = blockIdx.x, bj = blockIdx.y;
  if (bi > bj) return;
  __shared__ double sa[32][17];
  __shared__ double sb[16][33];
  const int t = threadIdx.x;
  const int ti = t & 15, tj = t >> 4;
  double a00=0,a01=0,a10=0,a11=0;
  for (int k0 = 0; k0 < 512; k0 += 16){
    { int ii = t >> 4, kk = t & 15;
      sa[ii][kk] = A[(size_t)(bi*32+ii)*512 + k0+kk];
      int ii2 = (t+256) >> 4, kk2 = (t+256) & 15;
      sa[ii2][kk2] = A[(size_t)(bi*32+ii2)*512 + k0+kk2];
      int kk3 = t >> 5, jj3 = t & 31;
      sb[kk3][jj3] = B[(size_t)(k0+kk3)*512 + bj*32+jj3];
      int kk4 = (t+256) >> 5, jj4 = (t+256) & 31;
      sb[kk4][jj4] = B[(size_t)(k0+kk4)*512 + bj*32+jj4];
    }
    __syncthreads();
    #pragma unroll
    for (int kk = 0; kk < 16; ++kk){
      double av0 = sa[ti][kk], av1 = sa[ti+16][kk];
      double bv0 = sb[kk][tj], bv1 = sb[kk][tj+16];
      a00 += av0*bv0; a01 += av0*bv1; a10 += av1*bv0; a11 += av1*bv1;
    }
    __syncthreads();
  }
  const int r0i = bi*32+ti, r1i = bi*32+ti+16, c0j = bj*32+tj, c1j = bj*32+tj+16;
  C[(size_t)r0i*512 + c0j] = a00;
  C[(size_t)r0i*512 + c1j] = a01;
  C[(size_t)r1i*512 + c0j] = a10;
  C[(size_t)r1i*512 + c1j] = a11;
  if (bi < bj){
    C[(size_t)c0j*512 + r0i] = a00;
    C[(size_t)c1j*512 + r0i] = a01;
    C[(size_t)c0j*512 + r1i] = a10;
    C[(size_t)c1j*512 + r1i] = a11;
  }
}

// ---------------- cooperative fused tail ----------------
union TailSmem {
  double red[256];
  double L[32][33];
  struct {
    double G[32][33], H[32][33], Q[32][33];
    double pcs[16], pss[16];
    int pp[16], pq[16], map[32], idx[10];
    double eig[32];
  } jac;
  struct {
    float cs[7][10];
    float fs[256][10];
    unsigned char labs[256];
    float sums[77];
  } km;
  struct {
    unsigned u[4096];
    int redc[4];
  } med;
};

__device__ __forceinline__ void matv_step(const double* __restrict__ M,
    const double* __restrict__ Vin, double* __restrict__ Vout, double scale, int gid){
  int r = gid >> 5, c = gid & 31;
  const double* Mr = M + (size_t)r*512;
  double s0=0,s1=0,s2=0,s3=0;
  for (int k = 0; k < 512; k += 4){
    s0 += Mr[k]   * Vin[(size_t)k*32 + c];
    s1 += Mr[k+1] * Vin[(size_t)(k+1)*32 + c];
    s2 += Mr[k+2] * Vin[(size_t)(k+2)*32 + c];
    s3 += Mr[k+3] * Vin[(size_t)(k+3)*32 + c];
  }
  Vout[gid] = ((s0+s1)+(s2+s3))*scale;
}

__global__ __launch_bounds__(256) void k_tail(
    const double* __restrict__ Cm, const double* __restrict__ C16m, const double* __restrict__ C64m,
    double* __restrict__ Va, double* __restrict__ Vb, double* __restrict__ Yb, double* __restrict__ Gm,
    const float* __restrict__ x, const double* __restrict__ meanbuf, float* __restrict__ Pm,
    float* __restrict__ feats, float* __restrict__ part2, float* __restrict__ distb,
    float* __restrict__ keep){
  cg::grid_group grid = cg::this_grid();
  __shared__ TailSmem sm;
  __shared__ double s_scal0, s_scal1;
  const int t = threadIdx.x;
  const int b = blockIdx.x;
  const int gid = b*256 + t;

  // S0: per-block redundant scale factors (exact: max is order-free)
  {
    double m0 = -1e300, m1 = -1e300;
    for (int i = t; i < 512; i += 256){
      m0 = fmax(m0, C16m[(size_t)i*512 + i]);
      m1 = fmax(m1, C64m[(size_t)i*512 + i]);
    }
    sm.red[t] = m0; __syncthreads();
    for (int o = 128; o; o >>= 1){ if (t < o) sm.red[t] = fmax(sm.red[t], sm.red[t+o]); __syncthreads(); }
    if (t == 0) s_scal0 = 1.0 / fmax(sm.red[0], 1e-300);
    __syncthreads();
    sm.red[t] = m1; __syncthreads();
    for (int o = 128; o; o >>= 1){ if (t < o) sm.red[t] = fmax(sm.red[t], sm.red[t+o]); __syncthreads(); }
    if (t == 0) s_scal1 = 1.0 / fmax(sm.red[0], 1e-300);
    __syncthreads();
  }

  // S1: init V0 (same hash/mapping as before)
  {
    unsigned h = (unsigned)gid * 2654435761u + 12345u;
    h ^= h >> 13; h *= 2246822519u; h ^= h >> 16;
    Va[gid] = ((double)(h & 0xffffu) / 32768.0) - 1.0;
  }
  grid.sync();

  // S2: 2 rounds of C^80 = C^64 * C^16 + Cholesky-QR
  for (int it = 0; it < 2; ++it){
    matv_step(C64m, Va, Vb, s_scal1, gid);
    grid.sync();
    matv_step(C16m, Vb, Va, s_scal0, gid);
    grid.sync();
    // Gram: 16 entries per block, serial dot (same order as before)
    if (t < 16){
      int e = b*16 + t; int i = e >> 5, j = e & 31;
      double s = 0;
      for (int k = 0; k < 512; ++k) s += Va[(size_t)k*32+i]*Va[(size_t)k*32+j];
      Gm[e] = s;
    }
    grid.sync();
    // Cholesky redundant per block; trsm rows b*8..b*8+7
    {
      for (int l = t; l < 1024; l += 256){ int i = l >> 5, j = l & 31; sm.L[i][j] = Gm[l]; }
      __syncthreads();
      for (int k = 0; k < 32; ++k){
        if (t == 0) sm.L[k][k] = sqrt(fmax(sm.L[k][k], 1e-300));
        __syncthreads();
        if (t > k && t < 32) sm.L[t][k] /= sm.L[k][k];
        __syncthreads();
        for (int l = t; l < 1024; l += 256){
          int i = l >> 5, j = l & 31;
          if (i > k && j > k && j <= i) sm.L[i][j] -= sm.L[i][k]*sm.L[j][k];
        }
        __syncthreads();
      }
      if (t < 8){
        int r = b*8 + t;
        double v[32];
        #pragma unroll
        for (int jj = 0; jj < 32; ++jj) v[jj] = Va[(size_t)r*32 + jj];
        #pragma unroll
        for (int jj = 0; jj < 32; ++jj){
          double s = v[jj];
          #pragma unroll
          for (int ii = 0; ii < 32; ++ii) if (ii < jj) s -= sm.L[jj][ii]*v[ii];
          v[jj] = s / sm.L[jj][jj];
        }
        #pragma unroll
        for (int jj = 0; jj < 32; ++jj) Va[(size_t)r*32 + jj] = v[jj];
      }
      __syncthreads();
    }
    grid.sync();
  }

  // S3: Yb = Cm * Va (scale 1.0 = identity)
  matv_step(Cm, Va, Yb, 1.0, gid);
  grid.sync();

  // S4: G = Va^T Yb (16 entries/block, serial dot)
  if (t < 16){
    int e = b*16 + t; int i = e >> 5, j = e & 31;
    double s = 0;
    for (int k = 0; k < 512; ++k) s += Va[(size_t)k*32+i]*Yb[(size_t)k*32+j];
    Gm[e] = s;
  }
  grid.sync();

  // S5: Jacobi (block 0 only, 5 sweeps, 4-wave version)
  if (b == 0){
    for (int l = t; l < 1024; l += 256){
      int i = l >> 5, j = l & 31;
      sm.jac.G[i][j] = 0.5*(Gm[i*32+j] + Gm[j*32+i]);
      sm.jac.Q[i][j] = (i == j) ? 1.0 : 0.0;
    }
    __syncthreads();
    for (int sweep = 0; sweep < 5; ++sweep)
    for (int r = 0; r < 31; ++r){
      if (t < 16){
        int u = (t == 0) ? 0 : ((r + t - 1) % 31) + 1;
        int v = ((r + 30 - t) % 31) + 1;
        int p_ = u < v ? u : v, q_ = u < v ? v : u;
        double app = sm.jac.G[p_][p_], aqq = sm.jac.G[q_][q_], apq = sm.jac.G[p_][q_];
        double c, s;
        if (fabs(apq) < 1e-280){ c = 1.0; s = 0.0; }
        else {
          double tau = (aqq - app)/(2.0*apq);
          double tt = (tau >= 0 ? 1.0 : -1.0)/(fabs(tau) + sqrt(1.0 + tau*tau));
          c = 1.0/sqrt(1.0 + tt*tt); s = tt*c;
        }
        sm.jac.pcs[t] = c; sm.jac.pss[t] = s; sm.jac.pp[t] = p_; sm.jac.pq[t] = q_;
        sm.jac.map[p_] = t; sm.jac.map[q_] = t | 32;
      }
      __syncthreads();
      for (int l = t; l < 1024; l += 256){
        int i = l >> 5, j = l & 31;
        int mi = sm.jac.map[i], k = mi & 31;
        double c = sm.jac.pcs[k], s = sm.jac.pss[k];
        double gp = sm.jac.G[sm.jac.pp[k]][j], gq = sm.jac.G[sm.jac.pq[k]][j];
        sm.jac.H[i][j] = (mi & 32) ? (s*gp + c*gq) : (c*gp - s*gq);
      }
      __syncthreads();
      for (int l = t; l < 512; l += 256){
        int i = l >> 4, k = l & 15;
        double c = sm.jac.pcs[k], s = sm.jac.pss[k];
        int p_ = sm.jac.pp[k], q_ = sm.jac.pq[k];
        double hp = sm.jac.H[i][p_], hq = sm.jac.H[i][q_];
        sm.jac.G[i][p_] = c*hp - s*hq; sm.jac.G[i][q_] = s*hp + c*hq;
        double qp = sm.jac.Q[i][p_], qq = sm.jac.Q[i][q_];
        sm.jac.Q[i][p_] = c*qp - s*qq; sm.jac.Q[i][q_] = s*qp + c*qq;
      }
      __syncthreads();
    }
    if (t == 0){
      for (int i2 = 0; i2 < 32; ++i2) sm.jac.eig[i2] = sm.jac.G[i2][i2];
      unsigned used = 0;
      for (int k = 0; k < 10; ++k){
        int best = 0; double bv = -1e300;
        for (int i2 = 0; i2 < 32; ++i2)
          if (!((used >> i2) & 1u) && sm.jac.eig[i2] > bv){ bv = sm.jac.eig[i2]; best = i2; }
        used |= 1u << best; sm.jac.idx[k] = best;
      }
    }
    __syncthreads();
    for (int l = t; l < 5120; l += 256){
      int k = l/10, j = l%10;
      int c = sm.jac.idx[j];
      double s2 = 0;
      for (int m = 0; m < 32; ++m) s2 += Va[(size_t)k*32+m]*sm.jac.Q[m][c];
      Pm[k*10+j] = (float)s2;
    }
  }
  grid.sync();

  // S6: feats = xc @ P  (grid-stride, same per-(n,j) serial loop)
  for (int id = gid; id < 65536; id += 16384){
    int n = id >> 4, j = id & 15;
    if (j < 10){
      float s = 0;
      for (int c2 = 0; c2 < 512; ++c2)
        s += (x[(size_t)n*512+c2] - (float)(meanbuf[c2]*(1.0/4096.0))) * Pm[c2*10+j];
      feats[n*10+j] = s;
    }
  }
  grid.sync();

  // S7: kmeans — 16 blocks own 256 points each; centroid update redundant per block
  if (t < 70) sm.km.cs[t/10][t%10] = feats[t];
  if (b < 16){
    int base = b*256;
    for (int i = t; i < 2560; i += 256) sm.km.fs[i/10][i%10] = feats[base*10 + i];
  }
  __syncthreads();
  for (int iter = 0; iter < 10; ++iter){
    float* pbuf = part2 + (size_t)(iter & 1)*16*77;
    if (b < 16){
      float f[10];
      #pragma unroll
      for (int d = 0; d < 10; ++d) f[d] = sm.km.fs[t][d];
      int best = 0; float bd = 3.0e38f;
      for (int k = 0; k < 7; ++k){
        float s = 0;
        #pragma unroll
        for (int d = 0; d < 10; ++d){ float df = f[d]-sm.km.cs[k][d]; s += df*df; }
        if (s < bd){ bd = s; best = k; }
      }
      sm.km.labs[t] = (unsigned char)best;
      __syncthreads();
      if (t < 77){
        float acc = 0;
        if (t < 70){
          int k = t/10, d = t%10;
          for (int nn = 0; nn < 256; ++nn) if (sm.km.labs[nn] == k) acc += sm.km.fs[nn][d];
        } else {
          int k = t - 70;
          for (int nn = 0; nn < 256; ++nn) if (sm.km.labs[nn] == k) acc += 1.f;
        }
        pbuf[b*77 + t] = acc;
      }
    }
    grid.sync();
    if (t < 77){
      float s = 0;
      for (int bb = 0; bb < 16; ++bb) s += pbuf[bb*77 + t];
      sm.km.sums[t] = s;
    }
    __syncthreads();
    if (t < 70){
      float cnt = sm.km.sums[70 + t/10];
      if (cnt > 0.f) sm.km.cs[t/10][t%10] = sm.km.sums[t] / fmaxf(cnt, 1.f);
    }
    __syncthreads();
  }
  // final distances
  if (b < 16){
    float f[10];
    #pragma unroll
    for (int d = 0; d < 10; ++d) f[d] = sm.km.fs[t][d];
    float bd = 3.0e38f;
    for (int k = 0; k < 7; ++k){
      float s = 0;
      #pragma unroll
      for (int d = 0; d < 10; ++d){ float df = f[d]-sm.km.cs[k][d]; s += df*df; }
      bd = fminf(bd, s);
    }
    distb[b*256 + t] = sqrtf(bd);
  }
  grid.sync();

  // S8: exact median (radix select) + keep, block 0 only
  if (b == 0){
    for (int i = t; i < 4096; i += 256) sm.med.u[i] = __float_as_uint(distb[i]);
    __syncthreads();
    unsigned vals[2];
    for (int ri = 0; ri < 2; ++ri){
      int r = 2047 + ri;
      unsigned prefix = 0;
      for (int bit = 31; bit >= 0; --bit){
        unsigned hm = (bit < 31) ? (0xffffffffu << (bit+1)) : 0u;
        int c = 0;
        for (int i = t; i < 4096; i += 256){
          unsigned e = sm.med.u[i];
          if ((e & hm) == prefix && !((e >> bit) & 1u)) c++;
        }
        #pragma unroll
        for (int o = 32; o; o >>= 1) c += __shfl_xor(c, o, 64);
        if ((t & 63) == 0) sm.med.redc[t >> 6] = c;
        __syncthreads();
        int tot = sm.med.redc[0] + sm.med.redc[1] + sm.med.redc[2] + sm.med.redc[3];
        if (r >= tot){ prefix |= (1u << bit); r -= tot; }
        __syncthreads();
      }
      vals[ri] = prefix;
    }
    float med = 0.5f*(__uint_as_float(vals[0]) + __uint_as_float(vals[1]));
    for (int i = t; i < 4096; i += 256) keep[i] = (distb[i] <= med) ? 1.f : 0.f;
  }
}

// ---------------- launch ----------------
extern "C" void kernel_launch(void* const* d_in, const int* in_sizes, int n_in,
                              void* d_out, int out_size, void* d_ws, size_t ws_size,
                              hipStream_t stream){
  const float* x      = (const float*)d_in[0];
  const float* W_ego  = (const float*)d_in[1];
  const float* b_ego  = (const float*)d_in[2];
  const float* W_cos  = (const float*)d_in[3];
  const float* b_cos  = (const float*)d_in[4];
  const float* W_glob = (const float*)d_in[5];
  const float* b_glob = (const float*)d_in[6];
  const float* W_fc   = (const float*)d_in[7];
  const float* b_fc   = (const float*)d_in[8];
  const int*   ei     = (const int*)d_in[9];
  const int* src = ei;
  const int* dst = ei + NE;
  float* out = (float*)d_out;

  char* p = (char*)d_ws;
  auto alloc = [&](size_t n) -> char* { char* r = p; p += (n + 255) & ~(size_t)255; return r; };

  unsigned long long* B1 = (unsigned long long*)alloc((size_t)NN*64*8);
  unsigned short* Mf     = (unsigned short*)alloc((size_t)NN*NN*2);
  unsigned short* x_bf   = (unsigned short*)alloc((size_t)NN*NC*2);
  unsigned short* xT_bf  = (unsigned short*)alloc((size_t)NN*NC*2);
  unsigned short* nx_bf  = (unsigned short*)alloc((size_t)NN*NC*2);
  unsigned short* egof   = (unsigned short*)alloc((size_t)NN*NC*2);
  unsigned short* cosf   = (unsigned short*)alloc((size_t)NN*NC*2);
  unsigned short* h_ego  = (unsigned short*)alloc((size_t)NN*NC*2);
  unsigned short* h_cos  = (unsigned short*)alloc((size_t)NN*NC*2);
  unsigned short* WegoT  = (unsigned short*)alloc((size_t)512*512*2);
  unsigned short* WcosT  = (unsigned short*)alloc((size_t)512*512*2);
  unsigned short* WglobT = (unsigned short*)alloc((size_t)512*512*2);
  unsigned short* WfcT   = (unsigned short*)alloc((size_t)128*2048*2);
  unsigned short* comb   = (unsigned short*)alloc((size_t)NN*2048*2);
  float* logits   = (float*)alloc((size_t)NN*64*4);
  float* rowrecip = (float*)alloc((size_t)NN*4);
  float* keep     = (float*)alloc((size_t)NN*4);
  int* cnt_in   = (int*)alloc((size_t)NN*4);
  int* cnt_out  = (int*)alloc((size_t)NN*4);
  int* off_in   = (int*)alloc((size_t)(NN+1)*4);
  int* off_out  = (int*)alloc((size_t)(NN+1)*4);
  int* fill_in  = (int*)alloc((size_t)NN*4);
  int* fill_out = (int*)alloc((size_t)NN*4);
  int* csr_in   = (int*)alloc((size_t)NE*4);
  int* csr_out  = (int*)alloc((size_t)NE*4);
  double* meanbuf = (double*)alloc(512*8);
  double* Cm  = (double*)alloc((size_t)512*512*8);
  double* C2m = (double*)alloc((size_t)512*512*8);
  double* C4m = (double*)alloc((size_t)512*512*8);
  double* C8m = (double*)alloc((size_t)512*512*8);
  double* C16m = (double*)alloc((size_t)512*512*8);
  double* C32m = (double*)alloc((size_t)512*512*8);
  double* C64m = (double*)alloc((size_t)512*512*8);
  double* Va  = (double*)alloc((size_t)512*32*8);
  double* Vb  = (double*)alloc((size_t)512*32*8);
  double* Yb  = (double*)alloc((size_t)512*32*8);
  double* Gm  = (double*)alloc(32*32*8);
  float* Pm    = (float*)alloc((size_t)512*10*4);
  float* feats = (float*)alloc((size_t)NN*10*4);
  float* part  = (float*)alloc((size_t)2*16*77*4);
  float* distb = (float*)alloc((size_t)NN*4);

  hipMemsetAsync(B1, 0, (size_t)NN*64*8, stream);
  hipMemsetAsync(cnt_in, 0, (size_t)NN*4, stream);
  hipMemsetAsync(cnt_out, 0, (size_t)NN*4, stream);
  hipMemsetAsync(meanbuf, 0, 512*8, stream);
  hipMemsetAsync(WfcT, 0, (size_t)128*2048*2, stream);

  // conversions
  k_transconv<<<dim3(8,64), 256, 0, stream>>>(x, NN, NC, xT_bf, NN, x_bf);
  k_transconv3<<<dim3(8,8,3), 256, 0, stream>>>(W_ego, W_cos, W_glob, WegoT, WcosT, WglobT);
  k_transconv<<<dim3(1,32), 256, 0, stream>>>(W_fc, 2048, 40, WfcT, 2048, (unsigned short*)0);
  k_normx<<<1024, 256, 0, stream>>>(x, nx_bf);

  // CSR + bitsets (fused edge pass)
  k_count_b1<<<512, 256, 0, stream>>>(src, dst, cnt_in, cnt_out, B1);
  k_scan<<<1, 1024, 0, stream>>>(cnt_in, cnt_out, off_in, off_out, fill_in, fill_out);
  k_fill<<<512, 256, 0, stream>>>(src, dst, fill_in, fill_out, csr_in, csr_out);
  k_bits2<<<1024, 256, 0, stream>>>(B1, off_in, csr_in, Mf, rowrecip);

  // ego_feats = (Mf @ x) / rowsum
  gemm_bt<0><<<dim3(64,4), 256, 0, stream>>>(Mf, NN, xT_bf, NN, NN, NC,
      (float*)0, egof, NC, (const float*)0, rowrecip);

  // dominant branch: big fp64 pieces (symmetric triangular + mirror)
  k_colmean<<<32, 256, 0, stream>>>(x, meanbuf);
  k_cov<<<dim3(16,16), 256, 0, stream>>>(x, meanbuf, Cm);
  k_mm64<<<dim3(16,16), 256, 0, stream>>>(Cm,  Cm,  C2m);
  k_mm64<<<dim3(16,16), 256, 0, stream>>>(C2m, C2m, C4m);
  k_mm64<<<dim3(16,16), 256, 0, stream>>>(C4m, C4m, C8m);
  k_mm64<<<dim3(16,16), 256, 0, stream>>>(C8m, C8m, C16m);
  k_mm64<<<dim3(16,16), 256, 0, stream>>>(C16m, C16m, C32m);
  k_mm64<<<dim3(16,16), 256, 0, stream>>>(C32m, C32m, C64m);

  // fused cooperative tail: subspace iter + Rayleigh-Ritz + Jacobi + feats + kmeans + median
  {
    void* args[] = { (void*)&Cm, (void*)&C16m, (void*)&C64m, (void*)&Va, (void*)&Vb,
                     (void*)&Yb, (void*)&Gm, (void*)&x, (void*)&meanbuf, (void*)&Pm,
                     (void*)&feats, (void*)&part, (void*)&distb, (void*)&keep };
    hipLaunchCooperativeKernel((void*)k_tail, dim3(64), dim3(256), args, 0, stream);
  }

  // cosine branch
  k_cos<<<1024, 256, 0, stream>>>(nx_bf, x_bf, off_out, csr_out, cosf);

  // encoders (three GEMMs in one launch, z selects)
  gemm_bt3<<<dim3(64,4,3), 256, 0, stream>>>(
      egof, cosf, x_bf,
      WegoT, WcosT, WglobT,
      b_ego, b_cos, b_glob,
      h_ego, h_cos, comb + 1536,
      2048);

  // aggregation + cut into combined (fused)
  k_aggcut<<<1024, 256, 0, stream>>>(h_ego, h_cos, off_in, csr_in, x_bf, keep, comb);

  // head + log_softmax
  gemm_bt<2><<<dim3(64,1), 256, 0, stream>>>(comb, 2048, WfcT, 2048, 2048, 40,
      logits, (unsigned short*)0, 64, b_fc, (const float*)0);
  k_lsm<<<1024, 256, 0, stream>>>(logits, out);
}

// Round 12
// 1735.394 us; speedup vs baseline: 1.0531x; 1.0152x over previous
//
#include <hip/hip_runtime.h>
#include <hip/hip_cooperative_groups.h>
#include <math.h>

namespace cg = cooperative_groups;

#define NN 4096
#define NC 512
#define NE 131072

typedef __bf16 bf16x8 __attribute__((ext_vector_type(8)));
typedef float f32x4 __attribute__((ext_vector_type(4)));
typedef unsigned short u16x8 __attribute__((ext_vector_type(8)));

__device__ __forceinline__ unsigned short f2b(float f){
  unsigned u = __float_as_uint(f);
  u += 0x7fffu + ((u >> 16) & 1u);
  return (unsigned short)(u >> 16);
}
__device__ __forceinline__ float b2f(unsigned short h){
  return __uint_as_float(((unsigned)h) << 16);
}
__device__ __forceinline__ float wredsum(float v){
  #pragma unroll
  for (int o = 32; o; o >>= 1) v += __shfl_xor(v, o, 64);
  return v;
}
__device__ __forceinline__ float wredmax(float v){
  #pragma unroll
  for (int o = 32; o; o >>= 1) v = fmaxf(v, __shfl_xor(v, o, 64));
  return v;
}

// ---------------- fused zeroing (replaces 4 memsets; WfcT left poisoned on purpose) ----------------
__global__ __launch_bounds__(256) void k_zero(unsigned long long* __restrict__ B1,
    int* __restrict__ cnt_in, int* __restrict__ cnt_out, double* __restrict__ meanbuf){
  int id = blockIdx.x*256 + threadIdx.x;           // 1024 blocks * 256 = 262144 threads
  // B1: 4096*64 u64 = 262144 elements
  B1[id] = 0ull;
  if (id < NN){ cnt_in[id] = 0; cnt_out[id] = 0; }
  if (id < 512) meanbuf[id] = 0.0;
}

// ---------------- conversions / transpose ----------------
__global__ __launch_bounds__(256) void k_transconv(const float* __restrict__ src, int R, int C,
    unsigned short* __restrict__ dstT, int ldT, unsigned short* __restrict__ dstD){
  __shared__ unsigned short tile[64][65];
  int bc = blockIdx.x * 64, br = blockIdx.y * 64;
  int t = threadIdx.x, lc = t & 63, lr4 = t >> 6;
  for (int j = 0; j < 16; ++j){
    int r = br + lr4*16 + j, c = bc + lc;
    float v = (r < R && c < C) ? src[(size_t)r*C + c] : 0.f;
    unsigned short b = f2b(v);
    tile[lr4*16+j][lc] = b;
    if (dstD && r < R && c < C) dstD[(size_t)r*C + c] = b;
  }
  __syncthreads();
  for (int j = 0; j < 16; ++j){
    int cc = bc + lr4*16 + j, rr = br + lc;
    if (cc < C && rr < R) dstT[(size_t)cc*ldT + rr] = tile[lc][lr4*16+j];
  }
}

// three 512x512 weight transposes in one launch (blockIdx.z selects matrix)
__global__ __launch_bounds__(256) void k_transconv3(const float* __restrict__ A,
    const float* __restrict__ B, const float* __restrict__ C,
    unsigned short* __restrict__ TA, unsigned short* __restrict__ TB, unsigned short* __restrict__ TC){
  __shared__ unsigned short tile[64][65];
  const float* src = (blockIdx.z == 0) ? A : ((blockIdx.z == 1) ? B : C);
  unsigned short* dstT = (blockIdx.z == 0) ? TA : ((blockIdx.z == 1) ? TB : TC);
  int bc = blockIdx.x * 64, br = blockIdx.y * 64;
  int t = threadIdx.x, lc = t & 63, lr4 = t >> 6;
  for (int j = 0; j < 16; ++j){
    int r = br + lr4*16 + j, c = bc + lc;
    tile[lr4*16+j][lc] = f2b(src[(size_t)r*512 + c]);
  }
  __syncthreads();
  for (int j = 0; j < 16; ++j){
    int cc = bc + lr4*16 + j, rr = br + lc;
    dstT[(size_t)cc*512 + rr] = tile[lc][lr4*16+j];
  }
}

__global__ __launch_bounds__(256) void k_normx(const float* __restrict__ x, unsigned short* __restrict__ nx){
  int wid = threadIdx.x >> 6, lane = threadIdx.x & 63;
  int row = blockIdx.x*4 + wid;
  const float* xr = x + (size_t)row*NC + lane*8;
  float v[8]; float ss = 0.f;
  #pragma unroll
  for (int j=0;j<8;j++){ v[j] = xr[j]; ss += v[j]*v[j]; }
  ss = wredsum(ss);
  float sc = 1.0f / fmaxf(sqrtf(ss), 1e-12f);
  u16x8 o;
  #pragma unroll
  for (int j=0;j<8;j++) o[j] = f2b(v[j]*sc);
  *(u16x8*)(nx + (size_t)row*NC + lane*8) = o;
}

// ---------------- CSR + 1-hop bitset (fused edge pass) ----------------
__global__ void k_count_b1(const int* __restrict__ src, const int* __restrict__ dst,
    int* cin, int* cout, unsigned long long* B1){
  int e = blockIdx.x*256 + threadIdx.x;
  if (e < NE){
    int s = src[e], d = dst[e];
    atomicAdd(&cout[s], 1);
    atomicAdd(&cin[d], 1);
    atomicOr(&B1[(size_t)d*64 + (s>>6)], 1ull << (s & 63));
  }
}
__global__ __launch_bounds__(1024) void k_scan(const int* __restrict__ cnt0, const int* __restrict__ cnt1,
    int* off0, int* off1, int* fill0, int* fill1){
  __shared__ int s[1024];
  int t = threadIdx.x;
  for (int arr = 0; arr < 2; ++arr){
    const int* cnt = arr ? cnt1 : cnt0;
    int* off = arr ? off1 : off0;
    int* fill = arr ? fill1 : fill0;
    int a0 = cnt[t*4], a1 = cnt[t*4+1], a2 = cnt[t*4+2], a3 = cnt[t*4+3];
    int ts = a0+a1+a2+a3;
    s[t] = ts; __syncthreads();
    for (int o = 1; o < 1024; o <<= 1){
      int v = (t >= o) ? s[t-o] : 0; __syncthreads();
      s[t] += v; __syncthreads();
    }
    int ex = s[t] - ts;
    off[t*4] = ex; off[t*4+1] = ex+a0; off[t*4+2] = ex+a0+a1; off[t*4+3] = ex+a0+a1+a2;
    fill[t*4] = ex; fill[t*4+1] = ex+a0; fill[t*4+2] = ex+a0+a1; fill[t*4+3] = ex+a0+a1+a2;
    if (t == 1023) off[4096] = s[1023];
    __syncthreads();
  }
}
__global__ void k_fill(const int* __restrict__ src, const int* __restrict__ dst,
    int* fin, int* fout, int* csr_in, int* csr_out){
  int e = blockIdx.x*256 + threadIdx.x;
  if (e < NE){
    int s = src[e], d = dst[e];
    int pi = atomicAdd(&fin[d], 1);  csr_in[pi] = s;
    int po = atomicAdd(&fout[s], 1); csr_out[po] = d;
  }
}

// ---------------- ego 2-hop bitsets -> dense bf16 Mf ----------------
__global__ __launch_bounds__(256) void k_bits2(const unsigned long long* __restrict__ B1,
    const int* __restrict__ off_in, const int* __restrict__ csr_in,
    unsigned short* __restrict__ Mf, float* __restrict__ rowrecip){
  int wid = threadIdx.x >> 6, lane = threadIdx.x & 63;
  int node = blockIdx.x*4 + wid;
  unsigned long long bits = B1[(size_t)node*64 + lane];
  if (lane == (node >> 6)) bits |= 1ull << (node & 63);
  int beg = off_in[node], end = off_in[node+1];
  for (int e = beg; e < end; ++e){
    int j = csr_in[e];
    bits |= B1[(size_t)j*64 + lane];
  }
  int pc = __popcll(bits);
  #pragma unroll
  for (int o = 32; o; o >>= 1) pc += __shfl_xor(pc, o, 64);
  if (lane == 0) rowrecip[node] = 1.0f / (float)pc;
  unsigned lo = (unsigned)(bits & 0xffffffffull), hi = (unsigned)(bits >> 32);
  unsigned int* Mrow = (unsigned int*)(Mf + (size_t)node*NN);
  for (int k = 0; k < 32; ++k){
    int srcl = 2*k + (lane >> 5);
    unsigned wlo = (unsigned)__shfl((int)lo, srcl, 64);
    unsigned whi = (unsigned)__shfl((int)hi, srcl, 64);
    unsigned long long w2 = ((unsigned long long)whi << 32) | wlo;
    int sh = (lane & 31) * 2;
    unsigned v = (unsigned)((w2 >> sh) & 3ull);
    Mrow[k*64 + lane] = ((v & 1u) ? 0x3F80u : 0u) | ((v & 2u) ? 0x3F800000u : 0u);
  }
}

// ---------------- bf16 MFMA GEMM: C(MxN) = A(MxK) @ BT(NxK)^T ----------------
template<int MODE>
__global__ __launch_bounds__(256) void gemm_bt(
    const unsigned short* __restrict__ A, int lda,
    const unsigned short* __restrict__ BT, int ldb,
    int K, int nstore,
    float* __restrict__ outF, unsigned short* __restrict__ outB, int ldc,
    const float* __restrict__ bias, const float* __restrict__ rowscale){
  __shared__ unsigned short Asm[64*40];
  __shared__ unsigned short Bsm[128*40];
  const int t = threadIdx.x;
  const int lane = t & 63, wid = t >> 6;
  const int wm = wid >> 1, wn = wid & 1;
  const int row0 = blockIdx.x * 64, col0 = blockIdx.y * 128;
  f32x4 acc[2][4];
  #pragma unroll
  for (int a = 0; a < 2; a++)
    #pragma unroll
    for (int b = 0; b < 4; b++){ acc[a][b][0]=0.f; acc[a][b][1]=0.f; acc[a][b][2]=0.f; acc[a][b][3]=0.f; }

  const int ar = t >> 2, as = t & 3;
  const unsigned short* Ap  = A  + (size_t)(row0 + ar)*lda + as*8;
  const unsigned short* Bp0 = BT + (size_t)(col0 + ar)*ldb + as*8;
  const unsigned short* Bp1 = BT + (size_t)(col0 + ar + 64)*ldb + as*8;
  unsigned short* Asd  = &Asm[ar*40 + as*8];
  unsigned short* Bsd0 = &Bsm[ar*40 + as*8];
  unsigned short* Bsd1 = &Bsm[(ar+64)*40 + as*8];

  const int fr = lane & 15, q = lane >> 4;
  const int aoff = (wm*32 + fr)*40 + q*8;
  const int boff = (wn*64 + fr)*40 + q*8;

  for (int k0 = 0; k0 < K; k0 += 32){
    *(u16x8*)Asd  = *(const u16x8*)(Ap  + k0);
    *(u16x8*)Bsd0 = *(const u16x8*)(Bp0 + k0);
    *(u16x8*)Bsd1 = *(const u16x8*)(Bp1 + k0);
    __syncthreads();
    bf16x8 af0 = *(const bf16x8*)&Asm[aoff];
    bf16x8 af1 = *(const bf16x8*)&Asm[aoff + 16*40];
    bf16x8 bfr[4];
    #pragma unroll
    for (int b = 0; b < 4; b++) bfr[b] = *(const bf16x8*)&Bsm[boff + b*16*40];
    #pragma unroll
    for (int b = 0; b < 4; b++){
      acc[0][b] = __builtin_amdgcn_mfma_f32_16x16x32_bf16(af0, bfr[b], acc[0][b], 0, 0, 0);
      acc[1][b] = __builtin_amdgcn_mfma_f32_16x16x32_bf16(af1, bfr[b], acc[1][b], 0, 0, 0);
    }
    __syncthreads();
  }
  #pragma unroll
  for (int a = 0; a < 2; a++){
    const int grow0 = row0 + wm*32 + a*16 + q*4;
    #pragma unroll
    for (int b = 0; b < 4; b++){
      const int gcol = col0 + wn*64 + b*16 + fr;
      if (gcol < nstore){
        #pragma unroll
        for (int r = 0; r < 4; r++){
          const int grow = grow0 + r;
          float v = acc[a][b][r];
          if (MODE == 0){ v *= rowscale[grow]; outB[(size_t)grow*ldc + gcol] = f2b(v); }
          if (MODE == 1){ v += bias[gcol];     outB[(size_t)grow*ldc + gcol] = f2b(v); }
          if (MODE == 2){ v += bias[gcol];     outF[(size_t)grow*ldc + gcol] = v; }
        }
      }
    }
  }
}

// three encoder GEMMs (M=4096,N=512,K=512, MODE1 semantics) in one launch, z selects
__global__ __launch_bounds__(256) void gemm_bt3(
    const unsigned short* __restrict__ A0, const unsigned short* __restrict__ A1, const unsigned short* __restrict__ A2,
    const unsigned short* __restrict__ B0, const unsigned short* __restrict__ B1g, const unsigned short* __restrict__ B2,
    const float* __restrict__ bias0, const float* __restrict__ bias1, const float* __restrict__ bias2,
    unsigned short* __restrict__ o0, unsigned short* __restrict__ o1, unsigned short* __restrict__ o2,
    int ldc2){
  const int z = blockIdx.z;
  const unsigned short* A  = (z == 0) ? A0 : ((z == 1) ? A1 : A2);
  const unsigned short* BT = (z == 0) ? B0 : ((z == 1) ? B1g : B2);
  const float* bias        = (z == 0) ? bias0 : ((z == 1) ? bias1 : bias2);
  unsigned short* outB     = (z == 0) ? o0 : ((z == 1) ? o1 : o2);
  const int ldc = (z == 2) ? ldc2 : 512;

  __shared__ unsigned short Asm[64*40];
  __shared__ unsigned short Bsm[128*40];
  const int t = threadIdx.x;
  const int lane = t & 63, wid = t >> 6;
  const int wm = wid >> 1, wn = wid & 1;
  const int row0 = blockIdx.x * 64, col0 = blockIdx.y * 128;
  f32x4 acc[2][4];
  #pragma unroll
  for (int a = 0; a < 2; a++)
    #pragma unroll
    for (int b = 0; b < 4; b++){ acc[a][b][0]=0.f; acc[a][b][1]=0.f; acc[a][b][2]=0.f; acc[a][b][3]=0.f; }

  const int ar = t >> 2, as = t & 3;
  const unsigned short* Ap  = A  + (size_t)(row0 + ar)*512 + as*8;
  const unsigned short* Bp0 = BT + (size_t)(col0 + ar)*512 + as*8;
  const unsigned short* Bp1 = BT + (size_t)(col0 + ar + 64)*512 + as*8;
  unsigned short* Asd  = &Asm[ar*40 + as*8];
  unsigned short* Bsd0 = &Bsm[ar*40 + as*8];
  unsigned short* Bsd1 = &Bsm[(ar+64)*40 + as*8];

  const int fr = lane & 15, q = lane >> 4;
  const int aoff = (wm*32 + fr)*40 + q*8;
  const int boff = (wn*64 + fr)*40 + q*8;

  for (int k0 = 0; k0 < 512; k0 += 32){
    *(u16x8*)Asd  = *(const u16x8*)(Ap  + k0);
    *(u16x8*)Bsd0 = *(const u16x8*)(Bp0 + k0);
    *(u16x8*)Bsd1 = *(const u16x8*)(Bp1 + k0);
    __syncthreads();
    bf16x8 af0 = *(const bf16x8*)&Asm[aoff];
    bf16x8 af1 = *(const bf16x8*)&Asm[aoff + 16*40];
    bf16x8 bfr[4];
    #pragma unroll
    for (int b = 0; b < 4; b++) bfr[b] = *(const bf16x8*)&Bsm[boff + b*16*40];
    #pragma unroll
    for (int b = 0; b < 4; b++){
      acc[0][b] = __builtin_amdgcn_mfma_f32_16x16x32_bf16(af0, bfr[b], acc[0][b], 0, 0, 0);
      acc[1][b] = __builtin_amdgcn_mfma_f32_16x16x32_bf16(af1, bfr[b], acc[1][b], 0, 0, 0);
    }
    __syncthreads();
  }
  #pragma unroll
  for (int a = 0; a < 2; a++){
    const int grow0 = row0 + wm*32 + a*16 + q*4;
    #pragma unroll
    for (int b = 0; b < 4; b++){
      const int gcol = col0 + wn*64 + b*16 + fr;
      #pragma unroll
      for (int r = 0; r < 4; r++){
        const int grow = grow0 + r;
        float v = acc[a][b][r] + bias[gcol];
        outB[(size_t)grow*ldc + gcol] = f2b(v);
      }
    }
  }
}

// head GEMM (M=4096,N=40 of 128,K=2048) with fused log_softmax epilogue
__global__ __launch_bounds__(256) void gemm_head(
    const unsigned short* __restrict__ A, const unsigned short* __restrict__ BT,
    const float* __restrict__ bias, float* __restrict__ out){
  __shared__ unsigned short Asm[64*40];
  __shared__ unsigned short Bsm[128*40];
  __shared__ float lg[64][41];
  const int t = threadIdx.x;
  const int lane = t & 63, wid = t >> 6;
  const int wm = wid >> 1, wn = wid & 1;
  const int row0 = blockIdx.x * 64;
  f32x4 acc[2][4];
  #pragma unroll
  for (int a = 0; a < 2; a++)
    #pragma unroll
    for (int b = 0; b < 4; b++){ acc[a][b][0]=0.f; acc[a][b][1]=0.f; acc[a][b][2]=0.f; acc[a][b][3]=0.f; }

  const int ar = t >> 2, as = t & 3;
  const unsigned short* Ap  = A  + (size_t)(row0 + ar)*2048 + as*8;
  const unsigned short* Bp0 = BT + (size_t)ar*2048 + as*8;
  const unsigned short* Bp1 = BT + (size_t)(ar + 64)*2048 + as*8;
  unsigned short* Asd  = &Asm[ar*40 + as*8];
  unsigned short* Bsd0 = &Bsm[ar*40 + as*8];
  unsigned short* Bsd1 = &Bsm[(ar+64)*40 + as*8];

  const int fr = lane & 15, q = lane >> 4;
  const int aoff = (wm*32 + fr)*40 + q*8;
  const int boff = (wn*64 + fr)*40 + q*8;

  for (int k0 = 0; k0 < 2048; k0 += 32){
    *(u16x8*)Asd  = *(const u16x8*)(Ap  + k0);
    *(u16x8*)Bsd0 = *(const u16x8*)(Bp0 + k0);
    *(u16x8*)Bsd1 = *(const u16x8*)(Bp1 + k0);
    __syncthreads();
    bf16x8 af0 = *(const bf16x8*)&Asm[aoff];
    bf16x8 af1 = *(const bf16x8*)&Asm[aoff + 16*40];
    bf16x8 bfr[4];
    #pragma unroll
    for (int b = 0; b < 4; b++) bfr[b] = *(const bf16x8*)&Bsm[boff + b*16*40];
    #pragma unroll
    for (int b = 0; b < 4; b++){
      acc[0][b] = __builtin_amdgcn_mfma_f32_16x16x32_bf16(af0, bfr[b], acc[0][b], 0, 0, 0);
      acc[1][b] = __builtin_amdgcn_mfma_f32_16x16x32_bf16(af1, bfr[b], acc[1][b], 0, 0, 0);
    }
    __syncthreads();
  }
  // stage logits (cols < 40 live in wn==0 waves) into LDS
  if (wn == 0){
    #pragma unroll
    for (int a = 0; a < 2; a++){
      const int lrow0 = wm*32 + a*16 + q*4;
      #pragma unroll
      for (int b = 0; b < 4; b++){
        const int gcol = b*16 + fr;
        if (gcol < 40){
          #pragma unroll
          for (int r = 0; r < 4; r++)
            lg[lrow0 + r][gcol] = acc[a][b][r] + bias[gcol];
        }
      }
    }
  }
  __syncthreads();
  // row-parallel log_softmax (output-side: summation-order change is ~1e-7, safe)
  if (t < 64){
    float m = -3.0e38f;
    #pragma unroll
    for (int j = 0; j < 40; ++j) m = fmaxf(m, lg[t][j]);
    float s = 0.f;
    #pragma unroll
    for (int j = 0; j < 40; ++j) s += expf(lg[t][j] - m);
    float l = logf(s);
    float* orow = out + (size_t)(row0 + t)*40;
    #pragma unroll
    for (int j = 0; j < 40; ++j) orow[j] = lg[t][j] - m - l;
  }
}

// ---------------- cosine branch ----------------
__global__ __launch_bounds__(256) void k_cos(const unsigned short* __restrict__ nx,
    const unsigned short* __restrict__ xb,
    const int* __restrict__ off_out, const int* __restrict__ csr_out,
    unsigned short* __restrict__ cosf){
  __shared__ float simsb[4][256];
  int wid = threadIdx.x >> 6, lane = threadIdx.x & 63;
  int node = blockIdx.x*4 + wid;
  float own[8];
  { u16x8 o = *(const u16x8*)(nx + (size_t)node*NC + lane*8);
    #pragma unroll
    for (int j=0;j<8;j++) own[j] = b2f(o[j]); }
  int beg = off_out[node], end = off_out[node+1], deg = end - beg;
  float m = -3.0e38f;
  for (int e = 0; e < deg; ++e){
    int d = csr_out[beg+e];
    u16x8 nb = *(const u16x8*)(nx + (size_t)d*NC + lane*8);
    float sp = 0.f;
    #pragma unroll
    for (int j=0;j<8;j++) sp += own[j]*b2f(nb[j]);
    float s = wredsum(sp);
    if (e < 256 && lane == 0) simsb[wid][e] = s;
    m = fmaxf(m, s);
  }
  float den = 0.f, acc[8] = {0,0,0,0,0,0,0,0};
  for (int e = 0; e < deg; ++e){
    int d = csr_out[beg+e];
    float s;
    if (e < 256) s = simsb[wid][e];
    else {
      u16x8 nb = *(const u16x8*)(nx + (size_t)d*NC + lane*8);
      float sp = 0.f;
      #pragma unroll
      for (int j=0;j<8;j++) sp += own[j]*b2f(nb[j]);
      s = wredsum(sp);
    }
    float w = expf(s - m);
    den += w;
    u16x8 xv = *(const u16x8*)(xb + (size_t)d*NC + lane*8);
    #pragma unroll
    for (int j=0;j<8;j++) acc[j] += w * b2f(xv[j]);
  }
  u16x8 o;
  if (deg > 0){
    float r = 1.0f/den;
    #pragma unroll
    for (int j=0;j<8;j++) o[j] = f2b(acc[j]*r);
  } else {
    o = *(const u16x8*)(xb + (size_t)node*NC + lane*8);
  }
  *(u16x8*)(cosf + (size_t)node*NC + lane*8) = o;
}

// ---------------- MP aggregation + relu + cut slice (fused) ----------------
__global__ __launch_bounds__(256) void k_aggcut(const unsigned short* __restrict__ he,
    const unsigned short* __restrict__ hc,
    const int* __restrict__ off_in, const int* __restrict__ csr_in,
    const unsigned short* __restrict__ xb, const float* __restrict__ keep,
    unsigned short* __restrict__ comb){
  int wid = threadIdx.x >> 6, lane = threadIdx.x & 63;
  int node = blockIdx.x*4 + wid;
  float ae[8] = {0,0,0,0,0,0,0,0}, ac[8] = {0,0,0,0,0,0,0,0};
  int beg = off_in[node], end = off_in[node+1];
  for (int e = beg; e < end; ++e){
    int j = csr_in[e];
    u16x8 ve = *(const u16x8*)(he + (size_t)j*NC + lane*8);
    u16x8 vc = *(const u16x8*)(hc + (size_t)j*NC + lane*8);
    #pragma unroll
    for (int k=0;k<8;k++){ ae[k] += b2f(ve[k]); ac[k] += b2f(vc[k]); }
  }
  u16x8 oe, oc;
  #pragma unroll
  for (int k=0;k<8;k++){ oe[k] = f2b(fmaxf(ae[k], 0.f)); oc[k] = f2b(fmaxf(ac[k], 0.f)); }
  *(u16x8*)(comb + (size_t)node*2048 + lane*8) = oe;
  *(u16x8*)(comb + (size_t)node*2048 + 1024 + lane*8) = oc;
  u16x8 xv = *(const u16x8*)(xb + (size_t)node*NC + lane*8);
  if (keep[node] == 0.f){
    #pragma unroll
    for (int j=0;j<8;j++) xv[j] = 0;
  }
  *(u16x8*)(comb + (size_t)node*2048 + 512 + lane*8) = xv;
}

// ---------------- dominant branch: big fp64 pieces ----------------
__global__ void k_colmean(const float* __restrict__ x, double* __restrict__ meanbuf){
  int c0 = threadIdx.x;
  int r0 = blockIdx.x*128;
  double s0 = 0, s1 = 0;
  for (int r = r0; r < r0+128; ++r){
    s0 += (double)x[(size_t)r*NC + c0];
    s1 += (double)x[(size_t)r*NC + c0 + 256];
  }
  atomicAdd(&meanbuf[c0], s0);
  atomicAdd(&meanbuf[c0+256], s1);
}

// symmetric: compute only bi<=bj blocks, mirror-store (bitwise identical)
__global__ __launch_bounds__(256) void k_cov(const float* __restrict__ x,
    const double* __restrict__ meanbuf, double* __restrict__ Cm){
  const int bi = blockIdx.x, bj = blockIdx.y;
  if (bi > bj) return;
  __shared__ float sa[16][33];
  __shared__ float sb[16][33];
  const int t = threadIdx.x;
  const int ti = t & 15, tj = t >> 4;
  int l0 = t, l1 = t + 256;
  int r0a = l0 >> 5, c0a = l0 & 31;
  int r1a = l1 >> 5, c1a = l1 & 31;
  float ma0 = (float)(meanbuf[bi*32 + c0a] * (1.0/4096.0));
  float ma1 = (float)(meanbuf[bi*32 + c1a] * (1.0/4096.0));
  float mb0 = (float)(meanbuf[bj*32 + c0a] * (1.0/4096.0));
  float mb1 = (float)(meanbuf[bj*32 + c1a] * (1.0/4096.0));
  double a00=0,a01=0,a10=0,a11=0;
  for (int r0 = 0; r0 < NN; r0 += 16){
    sa[r0a][c0a] = x[(size_t)(r0 + r0a)*NC + bi*32 + c0a] - ma0;
    sa[r1a][c1a] = x[(size_t)(r0 + r1a)*NC + bi*32 + c1a] - ma1;
    sb[r0a][c0a] = x[(size_t)(r0 + r0a)*NC + bj*32 + c0a] - mb0;
    sb[r1a][c1a] = x[(size_t)(r0 + r1a)*NC + bj*32 + c1a] - mb1;
    __syncthreads();
    #pragma unroll
    for (int rr = 0; rr < 16; ++rr){
      double av0 = (double)sa[rr][ti], av1 = (double)sa[rr][ti+16];
      double bv0 = (double)sb[rr][tj], bv1 = (double)sb[rr][tj+16];
      a00 += av0*bv0; a01 += av0*bv1; a10 += av1*bv0; a11 += av1*bv1;
    }
    __syncthreads();
  }
  const int r0i = bi*32+ti, r1i = bi*32+ti+16, c0j = bj*32+tj, c1j = bj*32+tj+16;
  Cm[(size_t)r0i*512 + c0j] = a00;
  Cm[(size_t)r0i*512 + c1j] = a01;
  Cm[(size_t)r1i*512 + c0j] = a10;
  Cm[(size_t)r1i*512 + c1j] = a11;
  if (bi < bj){
    Cm[(size_t)c0j*512 + r0i] = a00;
    Cm[(size_t)c1j*512 + r0i] = a01;
    Cm[(size_t)c0j*512 + r1i] = a10;
    Cm[(size_t)c1j*512 + r1i] = a11;
  }
}

// symmetric product of a symmetric matrix with itself: triangular + mirror (bitwise safe)
__global__ __launch_bounds__(256) void k_mm64(const double* __restrict__ A,
    const double* __restrict__ B, double* __restrict__ C){
  const int bi = blockIdx.x, bj = blockIdx.y;
  if (bi > bj) return;
  __shared__ double sa[32][17];
  __shared__ double sb[16][33];
  const int t = threadIdx.x;
  const int ti = t & 15, tj = t >> 4;
  double a00=0,a01=0,a10=0,a11=0;
  for (int k0 = 0; k0 < 512; k0 += 16){
    { int ii = t >> 4, kk = t & 15;
      sa[ii][kk] = A[(size_t)(bi*32+ii)*512 + k0+kk];
      int ii2 = (t+256) >> 4, kk2 = (t+256) & 15;
      sa[ii2][kk2] = A[(size_t)(bi*32+ii2)*512 + k0+kk2];
      int kk3 = t >> 5, jj3 = t & 31;
      sb[kk3][jj3] = B[(size_t)(k0+kk3)*512 + bj*32+jj3];
      int kk4 = (t+256) >> 5, jj4 = (t+256) & 31;
      sb[kk4][jj4] = B[(size_t)(k0+kk4)*512 + bj*32+jj4];
    }
    __syncthreads();
    #pragma unroll
    for (int kk = 0; kk < 16; ++kk){
      double av0 = sa[ti][kk], av1 = sa[ti+16][kk];
      double bv0 = sb[kk][tj], bv1 = sb[kk][tj+16];
      a00 += av0*bv0; a01 += av0*bv1; a10 += av1*bv0; a11 += av1*bv1;
    }
    __syncthreads();
  }
  const int r0i = bi*32+ti, r1i = bi*32+ti+16, c0j = bj*32+tj, c1j = bj*32+tj+16;
  C[(size_t)r0i*512 + c0j] = a00;
  C[(size_t)r0i*512 + c1j] = a01;
  C[(size_t)r1i*512 + c0j] = a10;
  C[(size_t)r1i*512 + c1j] = a11;
  if (bi < bj){
    C[(size_t)c0j*512 + r0i] = a00;
    C[(size_t)c1j*512 + r0i] = a01;
    C[(size_t)c0j*512 + r1i] = a10;
    C[(size_t)c1j*512 + r1i] = a11;
  }
}

// ---------------- cooperative fused tail (FROZEN — keep-path is chaotically sensitive) ----------------
union TailSmem {
  double red[256];
  double L[32][33];
  struct {
    double G[32][33], H[32][33], Q[32][33];
    double pcs[16], pss[16];
    int pp[16], pq[16], map[32], idx[10];
    double eig[32];
  } jac;
  struct {
    float cs[7][10];
    float fs[256][10];
    unsigned char labs[256];
    float sums[77];
  } km;
  struct {
    unsigned u[4096];
    int redc[4];
  } med;
};

__device__ __forceinline__ void matv_step(const double* __restrict__ M,
    const double* __restrict__ Vin, double* __restrict__ Vout, double scale, int gid){
  int r = gid >> 5, c = gid & 31;
  const double* Mr = M + (size_t)r*512;
  double s0=0,s1=0,s2=0,s3=0;
  for (int k = 0; k < 512; k += 4){
    s0 += Mr[k]   * Vin[(size_t)k*32 + c];
    s1 += Mr[k+1] * Vin[(size_t)(k+1)*32 + c];
    s2 += Mr[k+2] * Vin[(size_t)(k+2)*32 + c];
    s3 += Mr[k+3] * Vin[(size_t)(k+3)*32 + c];
  }
  Vout[gid] = ((s0+s1)+(s2+s3))*scale;
}

__global__ __launch_bounds__(256) void k_tail(
    const double* __restrict__ Cm, const double* __restrict__ C16m, const double* __restrict__ C64m,
    double* __restrict__ Va, double* __restrict__ Vb, double* __restrict__ Yb, double* __restrict__ Gm,
    const float* __restrict__ x, const double* __restrict__ meanbuf, float* __restrict__ Pm,
    float* __restrict__ feats, float* __restrict__ part2, float* __restrict__ distb,
    float* __restrict__ keep){
  cg::grid_group grid = cg::this_grid();
  __shared__ TailSmem sm;
  __shared__ double s_scal0, s_scal1;
  const int t = threadIdx.x;
  const int b = blockIdx.x;
  const int gid = b*256 + t;

  // S0: per-block redundant scale factors (exact: max is order-free)
  {
    double m0 = -1e300, m1 = -1e300;
    for (int i = t; i < 512; i += 256){
      m0 = fmax(m0, C16m[(size_t)i*512 + i]);
      m1 = fmax(m1, C64m[(size_t)i*512 + i]);
    }
    sm.red[t] = m0; __syncthreads();
    for (int o = 128; o; o >>= 1){ if (t < o) sm.red[t] = fmax(sm.red[t], sm.red[t+o]); __syncthreads(); }
    if (t == 0) s_scal0 = 1.0 / fmax(sm.red[0], 1e-300);
    __syncthreads();
    sm.red[t] = m1; __syncthreads();
    for (int o = 128; o; o >>= 1){ if (t < o) sm.red[t] = fmax(sm.red[t], sm.red[t+o]); __syncthreads(); }
    if (t == 0) s_scal1 = 1.0 / fmax(sm.red[0], 1e-300);
    __syncthreads();
  }

  // S1: init V0
  {
    unsigned h = (unsigned)gid * 2654435761u + 12345u;
    h ^= h >> 13; h *= 2246822519u; h ^= h >> 16;
    Va[gid] = ((double)(h & 0xffffu) / 32768.0) - 1.0;
  }
  grid.sync();

  // S2: 2 rounds of C^80 = C^64 * C^16 + Cholesky-QR
  for (int it = 0; it < 2; ++it){
    matv_step(C64m, Va, Vb, s_scal1, gid);
    grid.sync();
    matv_step(C16m, Vb, Va, s_scal0, gid);
    grid.sync();
    if (t < 16){
      int e = b*16 + t; int i = e >> 5, j = e & 31;
      double s = 0;
      for (int k = 0; k < 512; ++k) s += Va[(size_t)k*32+i]*Va[(size_t)k*32+j];
      Gm[e] = s;
    }
    grid.sync();
    {
      for (int l = t; l < 1024; l += 256){ int i = l >> 5, j = l & 31; sm.L[i][j] = Gm[l]; }
      __syncthreads();
      for (int k = 0; k < 32; ++k){
        if (t == 0) sm.L[k][k] = sqrt(fmax(sm.L[k][k], 1e-300));
        __syncthreads();
        if (t > k && t < 32) sm.L[t][k] /= sm.L[k][k];
        __syncthreads();
        for (int l = t; l < 1024; l += 256){
          int i = l >> 5, j = l & 31;
          if (i > k && j > k && j <= i) sm.L[i][j] -= sm.L[i][k]*sm.L[j][k];
        }
        __syncthreads();
      }
      if (t < 8){
        int r = b*8 + t;
        double v[32];
        #pragma unroll
        for (int jj = 0; jj < 32; ++jj) v[jj] = Va[(size_t)r*32 + jj];
        #pragma unroll
        for (int jj = 0; jj < 32; ++jj){
          double s = v[jj];
          #pragma unroll
          for (int ii = 0; ii < 32; ++ii) if (ii < jj) s -= sm.L[jj][ii]*v[ii];
          v[jj] = s / sm.L[jj][jj];
        }
        #pragma unroll
        for (int jj = 0; jj < 32; ++jj) Va[(size_t)r*32 + jj] = v[jj];
      }
      __syncthreads();
    }
    grid.sync();
  }

  // S3: Yb = Cm * Va
  matv_step(Cm, Va, Yb, 1.0, gid);
  grid.sync();

  // S4: G = Va^T Yb
  if (t < 16){
    int e = b*16 + t; int i = e >> 5, j = e & 31;
    double s = 0;
    for (int k = 0; k < 512; ++k) s += Va[(size_t)k*32+i]*Yb[(size_t)k*32+j];
    Gm[e] = s;
  }
  grid.sync();

  // S5: Jacobi (block 0 only, 5 sweeps)
  if (b == 0){
    for (int l = t; l < 1024; l += 256){
      int i = l >> 5, j = l & 31;
      sm.jac.G[i][j] = 0.5*(Gm[i*32+j] + Gm[j*32+i]);
      sm.jac.Q[i][j] = (i == j) ? 1.0 : 0.0;
    }
    __syncthreads();
    for (int sweep = 0; sweep < 5; ++sweep)
    for (int r = 0; r < 31; ++r){
      if (t < 16){
        int u = (t == 0) ? 0 : ((r + t - 1) % 31) + 1;
        int v = ((r + 30 - t) % 31) + 1;
        int p_ = u < v ? u : v, q_ = u < v ? v : u;
        double app = sm.jac.G[p_][p_], aqq = sm.jac.G[q_][q_], apq = sm.jac.G[p_][q_];
        double c, s;
        if (fabs(apq) < 1e-280){ c = 1.0; s = 0.0; }
        else {
          double tau = (aqq - app)/(2.0*apq);
          double tt = (tau >= 0 ? 1.0 : -1.0)/(fabs(tau) + sqrt(1.0 + tau*tau));
          c = 1.0/sqrt(1.0 + tt*tt); s = tt*c;
        }
        sm.jac.pcs[t] = c; sm.jac.pss[t] = s; sm.jac.pp[t] = p_; sm.jac.pq[t] = q_;
        sm.jac.map[p_] = t; sm.jac.map[q_] = t | 32;
      }
      __syncthreads();
      for (int l = t; l < 1024; l += 256){
        int i = l >> 5, j = l & 31;
        int mi = sm.jac.map[i], k = mi & 31;
        double c = sm.jac.pcs[k], s = sm.jac.pss[k];
        double gp = sm.jac.G[sm.jac.pp[k]][j], gq = sm.jac.G[sm.jac.pq[k]][j];
        sm.jac.H[i][j] = (mi & 32) ? (s*gp + c*gq) : (c*gp - s*gq);
      }
      __syncthreads();
      for (int l = t; l < 512; l += 256){
        int i = l >> 4, k = l & 15;
        double c = sm.jac.pcs[k], s = sm.jac.pss[k];
        int p_ = sm.jac.pp[k], q_ = sm.jac.pq[k];
        double hp = sm.jac.H[i][p_], hq = sm.jac.H[i][q_];
        sm.jac.G[i][p_] = c*hp - s*hq; sm.jac.G[i][q_] = s*hp + c*hq;
        double qp = sm.jac.Q[i][p_], qq = sm.jac.Q[i][q_];
        sm.jac.Q[i][p_] = c*qp - s*qq; sm.jac.Q[i][q_] = s*qp + c*qq;
      }
      __syncthreads();
    }
    if (t == 0){
      for (int i2 = 0; i2 < 32; ++i2) sm.jac.eig[i2] = sm.jac.G[i2][i2];
      unsigned used = 0;
      for (int k = 0; k < 10; ++k){
        int best = 0; double bv = -1e300;
        for (int i2 = 0; i2 < 32; ++i2)
          if (!((used >> i2) & 1u) && sm.jac.eig[i2] > bv){ bv = sm.jac.eig[i2]; best = i2; }
        used |= 1u << best; sm.jac.idx[k] = best;
      }
    }
    __syncthreads();
    for (int l = t; l < 5120; l += 256){
      int k = l/10, j = l%10;
      int c = sm.jac.idx[j];
      double s2 = 0;
      for (int m = 0; m < 32; ++m) s2 += Va[(size_t)k*32+m]*sm.jac.Q[m][c];
      Pm[k*10+j] = (float)s2;
    }
  }
  grid.sync();

  // S6: feats = xc @ P
  for (int id = gid; id < 65536; id += 16384){
    int n = id >> 4, j = id & 15;
    if (j < 10){
      float s = 0;
      for (int c2 = 0; c2 < 512; ++c2)
        s += (x[(size_t)n*512+c2] - (float)(meanbuf[c2]*(1.0/4096.0))) * Pm[c2*10+j];
      feats[n*10+j] = s;
    }
  }
  grid.sync();

  // S7: kmeans
  if (t < 70) sm.km.cs[t/10][t%10] = feats[t];
  if (b < 16){
    int base = b*256;
    for (int i = t; i < 2560; i += 256) sm.km.fs[i/10][i%10] = feats[base*10 + i];
  }
  __syncthreads();
  for (int iter = 0; iter < 10; ++iter){
    float* pbuf = part2 + (size_t)(iter & 1)*16*77;
    if (b < 16){
      float f[10];
      #pragma unroll
      for (int d = 0; d < 10; ++d) f[d] = sm.km.fs[t][d];
      int best = 0; float bd = 3.0e38f;
      for (int k = 0; k < 7; ++k){
        float s = 0;
        #pragma unroll
        for (int d = 0; d < 10; ++d){ float df = f[d]-sm.km.cs[k][d]; s += df*df; }
        if (s < bd){ bd = s; best = k; }
      }
      sm.km.labs[t] = (unsigned char)best;
      __syncthreads();
      if (t < 77){
        float acc = 0;
        if (t < 70){
          int k = t/10, d = t%10;
          for (int nn = 0; nn < 256; ++nn) if (sm.km.labs[nn] == k) acc += sm.km.fs[nn][d];
        } else {
          int k = t - 70;
          for (int nn = 0; nn < 256; ++nn) if (sm.km.labs[nn] == k) acc += 1.f;
        }
        pbuf[b*77 + t] = acc;
      }
    }
    grid.sync();
    if (t < 77){
      float s = 0;
      for (int bb = 0; bb < 16; ++bb) s += pbuf[bb*77 + t];
      sm.km.sums[t] = s;
    }
    __syncthreads();
    if (t < 70){
      float cnt = sm.km.sums[70 + t/10];
      if (cnt > 0.f) sm.km.cs[t/10][t%10] = sm.km.sums[t] / fmaxf(cnt, 1.f);
    }
    __syncthreads();
  }
  if (b < 16){
    float f[10];
    #pragma unroll
    for (int d = 0; d < 10; ++d) f[d] = sm.km.fs[t][d];
    float bd = 3.0e38f;
    for (int k = 0; k < 7; ++k){
      float s = 0;
      #pragma unroll
      for (int d = 0; d < 10; ++d){ float df = f[d]-sm.km.cs[k][d]; s += df*df; }
      bd = fminf(bd, s);
    }
    distb[b*256 + t] = sqrtf(bd);
  }
  grid.sync();

  // S8: exact median (radix select) + keep, block 0 only
  if (b == 0){
    for (int i = t; i < 4096; i += 256) sm.med.u[i] = __float_as_uint(distb[i]);
    __syncthreads();
    unsigned vals[2];
    for (int ri = 0; ri < 2; ++ri){
      int r = 2047 + ri;
      unsigned prefix = 0;
      for (int bit = 31; bit >= 0; --bit){
        unsigned hm = (bit < 31) ? (0xffffffffu << (bit+1)) : 0u;
        int c = 0;
        for (int i = t; i < 4096; i += 256){
          unsigned e = sm.med.u[i];
          if ((e & hm) == prefix && !((e >> bit) & 1u)) c++;
        }
        #pragma unroll
        for (int o = 32; o; o >>= 1) c += __shfl_xor(c, o, 64);
        if ((t & 63) == 0) sm.med.redc[t >> 6] = c;
        __syncthreads();
        int tot = sm.med.redc[0] + sm.med.redc[1] + sm.med.redc[2] + sm.med.redc[3];
        if (r >= tot){ prefix |= (1u << bit); r -= tot; }
        __syncthreads();
      }
      vals[ri] = prefix;
    }
    float med = 0.5f*(__uint_as_float(vals[0]) + __uint_as_float(vals[1]));
    for (int i = t; i < 4096; i += 256) keep[i] = (distb[i] <= med) ? 1.f : 0.f;
  }
}

// ---------------- launch ----------------
extern "C" void kernel_launch(void* const* d_in, const int* in_sizes, int n_in,
                              void* d_out, int out_size, void* d_ws, size_t ws_size,
                              hipStream_t stream){
  const float* x      = (const float*)d_in[0];
  const float* W_ego  = (const float*)d_in[1];
  const float* b_ego  = (const float*)d_in[2];
  const float* W_cos  = (const float*)d_in[3];
  const float* b_cos  = (const float*)d_in[4];
  const float* W_glob = (const float*)d_in[5];
  const float* b_glob = (const float*)d_in[6];
  const float* W_fc   = (const float*)d_in[7];
  const float* b_fc   = (const float*)d_in[8];
  const int*   ei     = (const int*)d_in[9];
  const int* src = ei;
  const int* dst = ei + NE;
  float* out = (float*)d_out;

  char* p = (char*)d_ws;
  auto alloc = [&](size_t n) -> char* { char* r = p; p += (n + 255) & ~(size_t)255; return r; };

  unsigned long long* B1 = (unsigned long long*)alloc((size_t)NN*64*8);
  unsigned short* Mf     = (unsigned short*)alloc((size_t)NN*NN*2);
  unsigned short* x_bf   = (unsigned short*)alloc((size_t)NN*NC*2);
  unsigned short* xT_bf  = (unsigned short*)alloc((size_t)NN*NC*2);
  unsigned short* nx_bf  = (unsigned short*)alloc((size_t)NN*NC*2);
  unsigned short* egof   = (unsigned short*)alloc((size_t)NN*NC*2);
  unsigned short* cosf   = (unsigned short*)alloc((size_t)NN*NC*2);
  unsigned short* h_ego  = (unsigned short*)alloc((size_t)NN*NC*2);
  unsigned short* h_cos  = (unsigned short*)alloc((size_t)NN*NC*2);
  unsigned short* WegoT  = (unsigned short*)alloc((size_t)512*512*2);
  unsigned short* WcosT  = (unsigned short*)alloc((size_t)512*512*2);
  unsigned short* WglobT = (unsigned short*)alloc((size_t)512*512*2);
  unsigned short* WfcT   = (unsigned short*)alloc((size_t)128*2048*2);
  unsigned short* comb   = (unsigned short*)alloc((size_t)NN*2048*2);
  float* rowrecip = (float*)alloc((size_t)NN*4);
  float* keep     = (float*)alloc((size_t)NN*4);
  int* cnt_in   = (int*)alloc((size_t)NN*4);
  int* cnt_out  = (int*)alloc((size_t)NN*4);
  int* off_in   = (int*)alloc((size_t)(NN+1)*4);
  int* off_out  = (int*)alloc((size_t)(NN+1)*4);
  int* fill_in  = (int*)alloc((size_t)NN*4);
  int* fill_out = (int*)alloc((size_t)NN*4);
  int* csr_in   = (int*)alloc((size_t)NE*4);
  int* csr_out  = (int*)alloc((size_t)NE*4);
  double* meanbuf = (double*)alloc(512*8);
  double* Cm  = (double*)alloc((size_t)512*512*8);
  double* C2m = (double*)alloc((size_t)512*512*8);
  double* C4m = (double*)alloc((size_t)512*512*8);
  double* C8m = (double*)alloc((size_t)512*512*8);
  double* C16m = (double*)alloc((size_t)512*512*8);
  double* C32m = (double*)alloc((size_t)512*512*8);
  double* C64m = (double*)alloc((size_t)512*512*8);
  double* Va  = (double*)alloc((size_t)512*32*8);
  double* Vb  = (double*)alloc((size_t)512*32*8);
  double* Yb  = (double*)alloc((size_t)512*32*8);
  double* Gm  = (double*)alloc(32*32*8);
  float* Pm    = (float*)alloc((size_t)512*10*4);
  float* feats = (float*)alloc((size_t)NN*10*4);
  float* part  = (float*)alloc((size_t)2*16*77*4);
  float* distb = (float*)alloc((size_t)NN*4);

  // fused zeroing (WfcT intentionally left poisoned: rows >=40 only feed discarded cols)
  k_zero<<<1024, 256, 0, stream>>>(B1, cnt_in, cnt_out, meanbuf);

  // conversions
  k_transconv<<<dim3(8,64), 256, 0, stream>>>(x, NN, NC, xT_bf, NN, x_bf);
  k_transconv3<<<dim3(8,8,3), 256, 0, stream>>>(W_ego, W_cos, W_glob, WegoT, WcosT, WglobT);
  k_transconv<<<dim3(1,32), 256, 0, stream>>>(W_fc, 2048, 40, WfcT, 2048, (unsigned short*)0);
  k_normx<<<1024, 256, 0, stream>>>(x, nx_bf);

  // CSR + bitsets (fused edge pass)
  k_count_b1<<<512, 256, 0, stream>>>(src, dst, cnt_in, cnt_out, B1);
  k_scan<<<1, 1024, 0, stream>>>(cnt_in, cnt_out, off_in, off_out, fill_in, fill_out);
  k_fill<<<512, 256, 0, stream>>>(src, dst, fill_in, fill_out, csr_in, csr_out);
  k_bits2<<<1024, 256, 0, stream>>>(B1, off_in, csr_in, Mf, rowrecip);

  // ego_feats = (Mf @ x) / rowsum
  gemm_bt<0><<<dim3(64,4), 256, 0, stream>>>(Mf, NN, xT_bf, NN, NN, NC,
      (float*)0, egof, NC, (const float*)0, rowrecip);

  // dominant branch: big fp64 pieces (symmetric triangular + mirror)
  k_colmean<<<32, 256, 0, stream>>>(x, meanbuf);
  k_cov<<<dim3(16,16), 256, 0, stream>>>(x, meanbuf, Cm);
  k_mm64<<<dim3(16,16), 256, 0, stream>>>(Cm,  Cm,  C2m);
  k_mm64<<<dim3(16,16), 256, 0, stream>>>(C2m, C2m, C4m);
  k_mm64<<<dim3(16,16), 256, 0, stream>>>(C4m, C4m, C8m);
  k_mm64<<<dim3(16,16), 256, 0, stream>>>(C8m, C8m, C16m);
  k_mm64<<<dim3(16,16), 256, 0, stream>>>(C16m, C16m, C32m);
  k_mm64<<<dim3(16,16), 256, 0, stream>>>(C32m, C32m, C64m);

  // fused cooperative tail (frozen numerics)
  {
    void* args[] = { (void*)&Cm, (void*)&C16m, (void*)&C64m, (void*)&Va, (void*)&Vb,
                     (void*)&Yb, (void*)&Gm, (void*)&x, (void*)&meanbuf, (void*)&Pm,
                     (void*)&feats, (void*)&part, (void*)&distb, (void*)&keep };
    hipLaunchCooperativeKernel((void*)k_tail, dim3(64), dim3(256), args, 0, stream);
  }

  // cosine branch
  k_cos<<<1024, 256, 0, stream>>>(nx_bf, x_bf, off_out, csr_out, cosf);

  // encoders (three GEMMs in one launch, z selects)
  gemm_bt3<<<dim3(64,4,3), 256, 0, stream>>>(
      egof, cosf, x_bf,
      WegoT, WcosT, WglobT,
      b_ego, b_cos, b_glob,
      h_ego, h_cos, comb + 1536,
      2048);

  // aggregation + cut into combined (fused)
  k_aggcut<<<1024, 256, 0, stream>>>(h_ego, h_cos, off_in, csr_in, x_bf, keep, comb);

  // head GEMM + fused log_softmax
  gemm_head<<<64, 256, 0, stream>>>(comb, WfcT, b_fc, out);
}

// Round 13
// 1666.329 us; speedup vs baseline: 1.0968x; 1.0414x over previous
//
#include <hip/hip_runtime.h>
#include <hip/hip_cooperative_groups.h>
#include <math.h>

namespace cg = cooperative_groups;

#define NN 4096
#define NC 512
#define NE 131072

typedef __bf16 bf16x8 __attribute__((ext_vector_type(8)));
typedef float f32x4 __attribute__((ext_vector_type(4)));
typedef unsigned short u16x8 __attribute__((ext_vector_type(8)));

__device__ __forceinline__ unsigned short f2b(float f){
  unsigned u = __float_as_uint(f);
  u += 0x7fffu + ((u >> 16) & 1u);
  return (unsigned short)(u >> 16);
}
__device__ __forceinline__ float b2f(unsigned short h){
  return __uint_as_float(((unsigned)h) << 16);
}
__device__ __forceinline__ float wredsum(float v){
  #pragma unroll
  for (int o = 32; o; o >>= 1) v += __shfl_xor(v, o, 64);
  return v;
}

// ---------------- fused zeroing ----------------
__global__ __launch_bounds__(256) void k_zero(unsigned long long* __restrict__ B1,
    int* __restrict__ cnt_in, int* __restrict__ cnt_out, double* __restrict__ meanbuf){
  int id = blockIdx.x*256 + threadIdx.x;
  B1[id] = 0ull;
  if (id < NN){ cnt_in[id] = 0; cnt_out[id] = 0; }
  if (id < 512) meanbuf[id] = 0.0;
}

// ---------------- conversions / transpose ----------------
__global__ __launch_bounds__(256) void k_transconv(const float* __restrict__ src, int R, int C,
    unsigned short* __restrict__ dstT, int ldT, unsigned short* __restrict__ dstD){
  __shared__ unsigned short tile[64][65];
  int bc = blockIdx.x * 64, br = blockIdx.y * 64;
  int t = threadIdx.x, lc = t & 63, lr4 = t >> 6;
  for (int j = 0; j < 16; ++j){
    int r = br + lr4*16 + j, c = bc + lc;
    float v = (r < R && c < C) ? src[(size_t)r*C + c] : 0.f;
    unsigned short b = f2b(v);
    tile[lr4*16+j][lc] = b;
    if (dstD && r < R && c < C) dstD[(size_t)r*C + c] = b;
  }
  __syncthreads();
  for (int j = 0; j < 16; ++j){
    int cc = bc + lr4*16 + j, rr = br + lc;
    if (cc < C && rr < R) dstT[(size_t)cc*ldT + rr] = tile[lc][lr4*16+j];
  }
}

// three 512x512 weight transposes in one launch
__global__ __launch_bounds__(256) void k_transconv3(const float* __restrict__ A,
    const float* __restrict__ B, const float* __restrict__ C,
    unsigned short* __restrict__ TA, unsigned short* __restrict__ TB, unsigned short* __restrict__ TC){
  __shared__ unsigned short tile[64][65];
  const float* src = (blockIdx.z == 0) ? A : ((blockIdx.z == 1) ? B : C);
  unsigned short* dstT = (blockIdx.z == 0) ? TA : ((blockIdx.z == 1) ? TB : TC);
  int bc = blockIdx.x * 64, br = blockIdx.y * 64;
  int t = threadIdx.x, lc = t & 63, lr4 = t >> 6;
  for (int j = 0; j < 16; ++j){
    int r = br + lr4*16 + j, c = bc + lc;
    tile[lr4*16+j][lc] = f2b(src[(size_t)r*512 + c]);
  }
  __syncthreads();
  for (int j = 0; j < 16; ++j){
    int cc = bc + lr4*16 + j, rr = br + lc;
    dstT[(size_t)cc*512 + rr] = tile[lc][lr4*16+j];
  }
}

// per-row inverse norms of x (fp32, matches reference 1/max(||x||,eps))
__global__ __launch_bounds__(256) void k_invnorm(const float* __restrict__ x, float* __restrict__ invn){
  int wid = threadIdx.x >> 6, lane = threadIdx.x & 63;
  int row = blockIdx.x*4 + wid;
  const float* xr = x + (size_t)row*NC + lane*8;
  float ss = 0.f;
  #pragma unroll
  for (int j=0;j<8;j++){ float v = xr[j]; ss += v*v; }
  ss = wredsum(ss);
  if (lane == 0) invn[row] = 1.0f / fmaxf(sqrtf(ss), 1e-12f);
}

// ---------------- CSR + 1-hop bitset (fused edge pass) ----------------
__global__ void k_count_b1(const int* __restrict__ src, const int* __restrict__ dst,
    int* cin, int* cout, unsigned long long* B1){
  int e = blockIdx.x*256 + threadIdx.x;
  if (e < NE){
    int s = src[e], d = dst[e];
    atomicAdd(&cout[s], 1);
    atomicAdd(&cin[d], 1);
    atomicOr(&B1[(size_t)d*64 + (s>>6)], 1ull << (s & 63));
  }
}
__global__ __launch_bounds__(1024) void k_scan(const int* __restrict__ cnt0, const int* __restrict__ cnt1,
    int* off0, int* off1, int* fill0, int* fill1){
  __shared__ int s[1024];
  int t = threadIdx.x;
  for (int arr = 0; arr < 2; ++arr){
    const int* cnt = arr ? cnt1 : cnt0;
    int* off = arr ? off1 : off0;
    int* fill = arr ? fill1 : fill0;
    int a0 = cnt[t*4], a1 = cnt[t*4+1], a2 = cnt[t*4+2], a3 = cnt[t*4+3];
    int ts = a0+a1+a2+a3;
    s[t] = ts; __syncthreads();
    for (int o = 1; o < 1024; o <<= 1){
      int v = (t >= o) ? s[t-o] : 0; __syncthreads();
      s[t] += v; __syncthreads();
    }
    int ex = s[t] - ts;
    off[t*4] = ex; off[t*4+1] = ex+a0; off[t*4+2] = ex+a0+a1; off[t*4+3] = ex+a0+a1+a2;
    fill[t*4] = ex; fill[t*4+1] = ex+a0; fill[t*4+2] = ex+a0+a1; fill[t*4+3] = ex+a0+a1+a2;
    if (t == 1023) off[4096] = s[1023];
    __syncthreads();
  }
}
__global__ void k_fill(const int* __restrict__ src, const int* __restrict__ dst,
    int* fin, int* fout, int* csr_in, int* csr_out){
  int e = blockIdx.x*256 + threadIdx.x;
  if (e < NE){
    int s = src[e], d = dst[e];
    int pi = atomicAdd(&fin[d], 1);  csr_in[pi] = s;
    int po = atomicAdd(&fout[s], 1); csr_out[po] = d;
  }
}

// ---------------- ego 2-hop bitsets -> dense bf16 Mf ----------------
__global__ __launch_bounds__(256) void k_bits2(const unsigned long long* __restrict__ B1,
    const int* __restrict__ off_in, const int* __restrict__ csr_in,
    unsigned short* __restrict__ Mf, float* __restrict__ rowrecip){
  int wid = threadIdx.x >> 6, lane = threadIdx.x & 63;
  int node = blockIdx.x*4 + wid;
  unsigned long long bits = B1[(size_t)node*64 + lane];
  if (lane == (node >> 6)) bits |= 1ull << (node & 63);
  int beg = off_in[node], end = off_in[node+1];
  for (int e = beg; e < end; ++e){
    int j = csr_in[e];
    bits |= B1[(size_t)j*64 + lane];
  }
  int pc = __popcll(bits);
  #pragma unroll
  for (int o = 32; o; o >>= 1) pc += __shfl_xor(pc, o, 64);
  if (lane == 0) rowrecip[node] = 1.0f / (float)pc;
  unsigned lo = (unsigned)(bits & 0xffffffffull), hi = (unsigned)(bits >> 32);
  unsigned int* Mrow = (unsigned int*)(Mf + (size_t)node*NN);
  for (int k = 0; k < 32; ++k){
    int srcl = 2*k + (lane >> 5);
    unsigned wlo = (unsigned)__shfl((int)lo, srcl, 64);
    unsigned whi = (unsigned)__shfl((int)hi, srcl, 64);
    unsigned long long w2 = ((unsigned long long)whi << 32) | wlo;
    int sh = (lane & 31) * 2;
    unsigned v = (unsigned)((w2 >> sh) & 3ull);
    Mrow[k*64 + lane] = ((v & 1u) ? 0x3F80u : 0u) | ((v & 2u) ? 0x3F800000u : 0u);
  }
}

// ---------------- bf16 MFMA GEMM: C(MxN) = A(MxK) @ BT(NxK)^T ----------------
template<int MODE>
__global__ __launch_bounds__(256) void gemm_bt(
    const unsigned short* __restrict__ A, int lda,
    const unsigned short* __restrict__ BT, int ldb,
    int K, int nstore,
    float* __restrict__ outF, unsigned short* __restrict__ outB, int ldc,
    const float* __restrict__ bias, const float* __restrict__ rowscale){
  __shared__ unsigned short Asm[64*40];
  __shared__ unsigned short Bsm[128*40];
  const int t = threadIdx.x;
  const int lane = t & 63, wid = t >> 6;
  const int wm = wid >> 1, wn = wid & 1;
  const int row0 = blockIdx.x * 64, col0 = blockIdx.y * 128;
  f32x4 acc[2][4];
  #pragma unroll
  for (int a = 0; a < 2; a++)
    #pragma unroll
    for (int b = 0; b < 4; b++){ acc[a][b][0]=0.f; acc[a][b][1]=0.f; acc[a][b][2]=0.f; acc[a][b][3]=0.f; }

  const int ar = t >> 2, as = t & 3;
  const unsigned short* Ap  = A  + (size_t)(row0 + ar)*lda + as*8;
  const unsigned short* Bp0 = BT + (size_t)(col0 + ar)*ldb + as*8;
  const unsigned short* Bp1 = BT + (size_t)(col0 + ar + 64)*ldb + as*8;
  unsigned short* Asd  = &Asm[ar*40 + as*8];
  unsigned short* Bsd0 = &Bsm[ar*40 + as*8];
  unsigned short* Bsd1 = &Bsm[(ar+64)*40 + as*8];

  const int fr = lane & 15, q = lane >> 4;
  const int aoff = (wm*32 + fr)*40 + q*8;
  const int boff = (wn*64 + fr)*40 + q*8;

  for (int k0 = 0; k0 < K; k0 += 32){
    *(u16x8*)Asd  = *(const u16x8*)(Ap  + k0);
    *(u16x8*)Bsd0 = *(const u16x8*)(Bp0 + k0);
    *(u16x8*)Bsd1 = *(const u16x8*)(Bp1 + k0);
    __syncthreads();
    bf16x8 af0 = *(const bf16x8*)&Asm[aoff];
    bf16x8 af1 = *(const bf16x8*)&Asm[aoff + 16*40];
    bf16x8 bfr[4];
    #pragma unroll
    for (int b = 0; b < 4; b++) bfr[b] = *(const bf16x8*)&Bsm[boff + b*16*40];
    #pragma unroll
    for (int b = 0; b < 4; b++){
      acc[0][b] = __builtin_amdgcn_mfma_f32_16x16x32_bf16(af0, bfr[b], acc[0][b], 0, 0, 0);
      acc[1][b] = __builtin_amdgcn_mfma_f32_16x16x32_bf16(af1, bfr[b], acc[1][b], 0, 0, 0);
    }
    __syncthreads();
  }
  #pragma unroll
  for (int a = 0; a < 2; a++){
    const int grow0 = row0 + wm*32 + a*16 + q*4;
    #pragma unroll
    for (int b = 0; b < 4; b++){
      const int gcol = col0 + wn*64 + b*16 + fr;
      if (gcol < nstore){
        #pragma unroll
        for (int r = 0; r < 4; r++){
          const int grow = grow0 + r;
          float v = acc[a][b][r];
          if (MODE == 0){ v *= rowscale[grow]; outB[(size_t)grow*ldc + gcol] = f2b(v); }
          if (MODE == 1){ v += bias[gcol];     outB[(size_t)grow*ldc + gcol] = f2b(v); }
          if (MODE == 2){ v += bias[gcol];     outF[(size_t)grow*ldc + gcol] = v; }
        }
      }
    }
  }
}

// three encoder GEMMs in one launch, z selects
__global__ __launch_bounds__(256) void gemm_bt3(
    const unsigned short* __restrict__ A0, const unsigned short* __restrict__ A1, const unsigned short* __restrict__ A2,
    const unsigned short* __restrict__ B0, const unsigned short* __restrict__ B1g, const unsigned short* __restrict__ B2,
    const float* __restrict__ bias0, const float* __restrict__ bias1, const float* __restrict__ bias2,
    unsigned short* __restrict__ o0, unsigned short* __restrict__ o1, unsigned short* __restrict__ o2,
    int ldc2){
  const int z = blockIdx.z;
  const unsigned short* A  = (z == 0) ? A0 : ((z == 1) ? A1 : A2);
  const unsigned short* BT = (z == 0) ? B0 : ((z == 1) ? B1g : B2);
  const float* bias        = (z == 0) ? bias0 : ((z == 1) ? bias1 : bias2);
  unsigned short* outB     = (z == 0) ? o0 : ((z == 1) ? o1 : o2);
  const int ldc = (z == 2) ? ldc2 : 512;

  __shared__ unsigned short Asm[64*40];
  __shared__ unsigned short Bsm[128*40];
  const int t = threadIdx.x;
  const int lane = t & 63, wid = t >> 6;
  const int wm = wid >> 1, wn = wid & 1;
  const int row0 = blockIdx.x * 64, col0 = blockIdx.y * 128;
  f32x4 acc[2][4];
  #pragma unroll
  for (int a = 0; a < 2; a++)
    #pragma unroll
    for (int b = 0; b < 4; b++){ acc[a][b][0]=0.f; acc[a][b][1]=0.f; acc[a][b][2]=0.f; acc[a][b][3]=0.f; }

  const int ar = t >> 2, as = t & 3;
  const unsigned short* Ap  = A  + (size_t)(row0 + ar)*512 + as*8;
  const unsigned short* Bp0 = BT + (size_t)(col0 + ar)*512 + as*8;
  const unsigned short* Bp1 = BT + (size_t)(col0 + ar + 64)*512 + as*8;
  unsigned short* Asd  = &Asm[ar*40 + as*8];
  unsigned short* Bsd0 = &Bsm[ar*40 + as*8];
  unsigned short* Bsd1 = &Bsm[(ar+64)*40 + as*8];

  const int fr = lane & 15, q = lane >> 4;
  const int aoff = (wm*32 + fr)*40 + q*8;
  const int boff = (wn*64 + fr)*40 + q*8;

  for (int k0 = 0; k0 < 512; k0 += 32){
    *(u16x8*)Asd  = *(const u16x8*)(Ap  + k0);
    *(u16x8*)Bsd0 = *(const u16x8*)(Bp0 + k0);
    *(u16x8*)Bsd1 = *(const u16x8*)(Bp1 + k0);
    __syncthreads();
    bf16x8 af0 = *(const bf16x8*)&Asm[aoff];
    bf16x8 af1 = *(const bf16x8*)&Asm[aoff + 16*40];
    bf16x8 bfr[4];
    #pragma unroll
    for (int b = 0; b < 4; b++) bfr[b] = *(const bf16x8*)&Bsm[boff + b*16*40];
    #pragma unroll
    for (int b = 0; b < 4; b++){
      acc[0][b] = __builtin_amdgcn_mfma_f32_16x16x32_bf16(af0, bfr[b], acc[0][b], 0, 0, 0);
      acc[1][b] = __builtin_amdgcn_mfma_f32_16x16x32_bf16(af1, bfr[b], acc[1][b], 0, 0, 0);
    }
    __syncthreads();
  }
  #pragma unroll
  for (int a = 0; a < 2; a++){
    const int grow0 = row0 + wm*32 + a*16 + q*4;
    #pragma unroll
    for (int b = 0; b < 4; b++){
      const int gcol = col0 + wn*64 + b*16 + fr;
      #pragma unroll
      for (int r = 0; r < 4; r++){
        const int grow = grow0 + r;
        float v = acc[a][b][r] + bias[gcol];
        outB[(size_t)grow*ldc + gcol] = f2b(v);
      }
    }
  }
}

// head GEMM (M=4096,N=40 of 128,K=2048) with fused log_softmax epilogue
__global__ __launch_bounds__(256) void gemm_head(
    const unsigned short* __restrict__ A, const unsigned short* __restrict__ BT,
    const float* __restrict__ bias, float* __restrict__ out){
  __shared__ unsigned short Asm[64*40];
  __shared__ unsigned short Bsm[128*40];
  __shared__ float lg[64][41];
  const int t = threadIdx.x;
  const int lane = t & 63, wid = t >> 6;
  const int wm = wid >> 1, wn = wid & 1;
  const int row0 = blockIdx.x * 64;
  f32x4 acc[2][4];
  #pragma unroll
  for (int a = 0; a < 2; a++)
    #pragma unroll
    for (int b = 0; b < 4; b++){ acc[a][b][0]=0.f; acc[a][b][1]=0.f; acc[a][b][2]=0.f; acc[a][b][3]=0.f; }

  const int ar = t >> 2, as = t & 3;
  const unsigned short* Ap  = A  + (size_t)(row0 + ar)*2048 + as*8;
  const unsigned short* Bp0 = BT + (size_t)ar*2048 + as*8;
  const unsigned short* Bp1 = BT + (size_t)(ar + 64)*2048 + as*8;
  unsigned short* Asd  = &Asm[ar*40 + as*8];
  unsigned short* Bsd0 = &Bsm[ar*40 + as*8];
  unsigned short* Bsd1 = &Bsm[(ar+64)*40 + as*8];

  const int fr = lane & 15, q = lane >> 4;
  const int aoff = (wm*32 + fr)*40 + q*8;
  const int boff = (wn*64 + fr)*40 + q*8;

  for (int k0 = 0; k0 < 2048; k0 += 32){
    *(u16x8*)Asd  = *(const u16x8*)(Ap  + k0);
    *(u16x8*)Bsd0 = *(const u16x8*)(Bp0 + k0);
    *(u16x8*)Bsd1 = *(const u16x8*)(Bp1 + k0);
    __syncthreads();
    bf16x8 af0 = *(const bf16x8*)&Asm[aoff];
    bf16x8 af1 = *(const bf16x8*)&Asm[aoff + 16*40];
    bf16x8 bfr[4];
    #pragma unroll
    for (int b = 0; b < 4; b++) bfr[b] = *(const bf16x8*)&Bsm[boff + b*16*40];
    #pragma unroll
    for (int b = 0; b < 4; b++){
      acc[0][b] = __builtin_amdgcn_mfma_f32_16x16x32_bf16(af0, bfr[b], acc[0][b], 0, 0, 0);
      acc[1][b] = __builtin_amdgcn_mfma_f32_16x16x32_bf16(af1, bfr[b], acc[1][b], 0, 0, 0);
    }
    __syncthreads();
  }
  if (wn == 0){
    #pragma unroll
    for (int a = 0; a < 2; a++){
      const int lrow0 = wm*32 + a*16 + q*4;
      #pragma unroll
      for (int b = 0; b < 4; b++){
        const int gcol = b*16 + fr;
        if (gcol < 40){
          #pragma unroll
          for (int r = 0; r < 4; r++)
            lg[lrow0 + r][gcol] = acc[a][b][r] + bias[gcol];
        }
      }
    }
  }
  __syncthreads();
  if (t < 64){
    float m = -3.0e38f;
    #pragma unroll
    for (int j = 0; j < 40; ++j) m = fmaxf(m, lg[t][j]);
    float s = 0.f;
    #pragma unroll
    for (int j = 0; j < 40; ++j) s += expf(lg[t][j] - m);
    float l = logf(s);
    float* orow = out + (size_t)(row0 + t)*40;
    #pragma unroll
    for (int j = 0; j < 40; ++j) orow[j] = lg[t][j] - m - l;
  }
}

// ---------------- cosine branch (single pass; raw bf16 rows + inv-norms) ----------------
// s = (x_i . x_d) * inv_i * inv_d; w = exp(s) (sims in [-1,1]: no overflow, softmax
// ratios unchanged). Output-side continuous path: ~2e-4 perturbation << bf16 floor.
__global__ __launch_bounds__(256) void k_cos(const unsigned short* __restrict__ xb,
    const float* __restrict__ invn,
    const int* __restrict__ off_out, const int* __restrict__ csr_out,
    unsigned short* __restrict__ cosf){
  int wid = threadIdx.x >> 6, lane = threadIdx.x & 63;
  int node = blockIdx.x*4 + wid;
  float own[8];
  { u16x8 o = *(const u16x8*)(xb + (size_t)node*NC + lane*8);
    #pragma unroll
    for (int j=0;j<8;j++) own[j] = b2f(o[j]); }
  float inv_i = invn[node];
  int beg = off_out[node], end = off_out[node+1], deg = end - beg;
  float den = 0.f, acc[8] = {0,0,0,0,0,0,0,0};
  for (int e = 0; e < deg; ++e){
    int d = csr_out[beg+e];
    u16x8 xv = *(const u16x8*)(xb + (size_t)d*NC + lane*8);
    float xd[8];
    #pragma unroll
    for (int j=0;j<8;j++) xd[j] = b2f(xv[j]);
    float sp = 0.f;
    #pragma unroll
    for (int j=0;j<8;j++) sp += own[j]*xd[j];
    float s = wredsum(sp) * inv_i * invn[d];
    float w = expf(s);
    den += w;
    #pragma unroll
    for (int j=0;j<8;j++) acc[j] += w * xd[j];
  }
  u16x8 o;
  if (deg > 0){
    float r = 1.0f/den;
    #pragma unroll
    for (int j=0;j<8;j++) o[j] = f2b(acc[j]*r);
  } else {
    o = *(const u16x8*)(xb + (size_t)node*NC + lane*8);
  }
  *(u16x8*)(cosf + (size_t)node*NC + lane*8) = o;
}

// ---------------- MP aggregation + relu + cut slice (fused) ----------------
__global__ __launch_bounds__(256) void k_aggcut(const unsigned short* __restrict__ he,
    const unsigned short* __restrict__ hc,
    const int* __restrict__ off_in, const int* __restrict__ csr_in,
    const unsigned short* __restrict__ xb, const float* __restrict__ keep,
    unsigned short* __restrict__ comb){
  int wid = threadIdx.x >> 6, lane = threadIdx.x & 63;
  int node = blockIdx.x*4 + wid;
  float ae[8] = {0,0,0,0,0,0,0,0}, ac[8] = {0,0,0,0,0,0,0,0};
  int beg = off_in[node], end = off_in[node+1];
  for (int e = beg; e < end; ++e){
    int j = csr_in[e];
    u16x8 ve = *(const u16x8*)(he + (size_t)j*NC + lane*8);
    u16x8 vc = *(const u16x8*)(hc + (size_t)j*NC + lane*8);
    #pragma unroll
    for (int k=0;k<8;k++){ ae[k] += b2f(ve[k]); ac[k] += b2f(vc[k]); }
  }
  u16x8 oe, oc;
  #pragma unroll
  for (int k=0;k<8;k++){ oe[k] = f2b(fmaxf(ae[k], 0.f)); oc[k] = f2b(fmaxf(ac[k], 0.f)); }
  *(u16x8*)(comb + (size_t)node*2048 + lane*8) = oe;
  *(u16x8*)(comb + (size_t)node*2048 + 1024 + lane*8) = oc;
  u16x8 xv = *(const u16x8*)(xb + (size_t)node*NC + lane*8);
  if (keep[node] == 0.f){
    #pragma unroll
    for (int j=0;j<8;j++) xv[j] = 0;
  }
  *(u16x8*)(comb + (size_t)node*2048 + 512 + lane*8) = xv;
}

// ---------------- dominant branch: big fp64 pieces ----------------
__global__ void k_colmean(const float* __restrict__ x, double* __restrict__ meanbuf){
  int c0 = threadIdx.x;
  int r0 = blockIdx.x*128;
  double s0 = 0, s1 = 0;
  for (int r = r0; r < r0+128; ++r){
    s0 += (double)x[(size_t)r*NC + c0];
    s1 += (double)x[(size_t)r*NC + c0 + 256];
  }
  atomicAdd(&meanbuf[c0], s0);
  atomicAdd(&meanbuf[c0+256], s1);
}

// symmetric: compute only bi<=bj blocks, mirror-store (bitwise identical)
__global__ __launch_bounds__(256) void k_cov(const float* __restrict__ x,
    const double* __restrict__ meanbuf, double* __restrict__ Cm){
  const int bi = blockIdx.x, bj = blockIdx.y;
  if (bi > bj) return;
  __shared__ float sa[16][33];
  __shared__ float sb[16][33];
  const int t = threadIdx.x;
  const int ti = t & 15, tj = t >> 4;
  int l0 = t, l1 = t + 256;
  int r0a = l0 >> 5, c0a = l0 & 31;
  int r1a = l1 >> 5, c1a = l1 & 31;
  float ma0 = (float)(meanbuf[bi*32 + c0a] * (1.0/4096.0));
  float ma1 = (float)(meanbuf[bi*32 + c1a] * (1.0/4096.0));
  float mb0 = (float)(meanbuf[bj*32 + c0a] * (1.0/4096.0));
  float mb1 = (float)(meanbuf[bj*32 + c1a] * (1.0/4096.0));
  double a00=0,a01=0,a10=0,a11=0;
  for (int r0 = 0; r0 < NN; r0 += 16){
    sa[r0a][c0a] = x[(size_t)(r0 + r0a)*NC + bi*32 + c0a] - ma0;
    sa[r1a][c1a] = x[(size_t)(r0 + r1a)*NC + bi*32 + c1a] - ma1;
    sb[r0a][c0a] = x[(size_t)(r0 + r0a)*NC + bj*32 + c0a] - mb0;
    sb[r1a][c1a] = x[(size_t)(r0 + r1a)*NC + bj*32 + c1a] - mb1;
    __syncthreads();
    #pragma unroll
    for (int rr = 0; rr < 16; ++rr){
      double av0 = (double)sa[rr][ti], av1 = (double)sa[rr][ti+16];
      double bv0 = (double)sb[rr][tj], bv1 = (double)sb[rr][tj+16];
      a00 += av0*bv0; a01 += av0*bv1; a10 += av1*bv0; a11 += av1*bv1;
    }
    __syncthreads();
  }
  const int r0i = bi*32+ti, r1i = bi*32+ti+16, c0j = bj*32+tj, c1j = bj*32+tj+16;
  Cm[(size_t)r0i*512 + c0j] = a00;
  Cm[(size_t)r0i*512 + c1j] = a01;
  Cm[(size_t)r1i*512 + c0j] = a10;
  Cm[(size_t)r1i*512 + c1j] = a11;
  if (bi < bj){
    Cm[(size_t)c0j*512 + r0i] = a00;
    Cm[(size_t)c1j*512 + r0i] = a01;
    Cm[(size_t)c0j*512 + r1i] = a10;
    Cm[(size_t)c1j*512 + r1i] = a11;
  }
}

// symmetric product of a symmetric matrix with itself (bitwise safe)
__global__ __launch_bounds__(256) void k_mm64(const double* __restrict__ A,
    const double* __restrict__ B, double* __restrict__ C){
  const int bi = blockIdx.x, bj = blockIdx.y;
  if (bi > bj) return;
  __shared__ double sa[32][17];
  __shared__ double sb[16][33];
  const int t = threadIdx.x;
  const int ti = t & 15, tj = t >> 4;
  double a00=0,a01=0,a10=0,a11=0;
  for (int k0 = 0; k0 < 512; k0 += 16){
    { int ii = t >> 4, kk = t & 15;
      sa[ii][kk] = A[(size_t)(bi*32+ii)*512 + k0+kk];
      int ii2 = (t+256) >> 4, kk2 = (t+256) & 15;
      sa[ii2][kk2] = A[(size_t)(bi*32+ii2)*512 + k0+kk2];
      int kk3 = t >> 5, jj3 = t & 31;
      sb[kk3][jj3] = B[(size_t)(k0+kk3)*512 + bj*32+jj3];
      int kk4 = (t+256) >> 5, jj4 = (t+256) & 31;
      sb[kk4][jj4] = B[(size_t)(k0+kk4)*512 + bj*32+jj4];
    }
    __syncthreads();
    #pragma unroll
    for (int kk = 0; kk < 16; ++kk){
      double av0 = sa[ti][kk], av1 = sa[ti+16][kk];
      double bv0 = sb[kk][tj], bv1 = sb[kk][tj+16];
      a00 += av0*bv0; a01 += av0*bv1; a10 += av1*bv0; a11 += av1*bv1;
    }
    __syncthreads();
  }
  const int r0i = bi*32+ti, r1i = bi*32+ti+16, c0j = bj*32+tj, c1j = bj*32+tj+16;
  C[(size_t)r0i*512 + c0j] = a00;
  C[(size_t)r0i*512 + c1j] = a01;
  C[(size_t)r1i*512 + c0j] = a10;
  C[(size_t)r1i*512 + c1j] = a11;
  if (bi < bj){
    C[(size_t)c0j*512 + r0i] = a00;
    C[(size_t)c1j*512 + r0i] = a01;
    C[(size_t)c0j*512 + r1i] = a10;
    C[(size_t)c1j*512 + r1i] = a11;
  }
}

// ---------------- cooperative fused tail (keep-path numerics FROZEN) ----------------
union TailSmem {
  double red[256];
  double L[32][33];
  struct {
    double G[32][33], H[32][33], Q[32][33];
    double pcs[16], pss[16];
    int pp[16], pq[16], map[32], idx[10];
    double eig[32];
  } jac;
  struct {
    float Ps[512][10];
    float cm[512];
  } ft;
  struct {
    float cs[7][10];
    float fs[256][10];
    unsigned char labs[256];
    float sums[77];
  } km;
  struct {
    unsigned u[4096];
    int redc[4];
  } med;
};

__device__ __forceinline__ void matv_step(const double* __restrict__ M,
    const double* __restrict__ Vin, double* __restrict__ Vout, double scale, int gid){
  int r = gid >> 5, c = gid & 31;
  const double* Mr = M + (size_t)r*512;
  double s0=0,s1=0,s2=0,s3=0;
  for (int k = 0; k < 512; k += 4){
    s0 += Mr[k]   * Vin[(size_t)k*32 + c];
    s1 += Mr[k+1] * Vin[(size_t)(k+1)*32 + c];
    s2 += Mr[k+2] * Vin[(size_t)(k+2)*32 + c];
    s3 += Mr[k+3] * Vin[(size_t)(k+3)*32 + c];
  }
  Vout[gid] = ((s0+s1)+(s2+s3))*scale;
}

__global__ __launch_bounds__(256) void k_tail(
    const double* __restrict__ Cm, const double* __restrict__ C16m, const double* __restrict__ C64m,
    double* __restrict__ Va, double* __restrict__ Vb, double* __restrict__ Yb, double* __restrict__ Gm,
    const float* __restrict__ x, const double* __restrict__ meanbuf, float* __restrict__ Pm,
    float* __restrict__ feats, float* __restrict__ part2, float* __restrict__ distb,
    float* __restrict__ keep){
  cg::grid_group grid = cg::this_grid();
  __shared__ TailSmem sm;
  __shared__ double s_scal0, s_scal1;
  const int t = threadIdx.x;
  const int b = blockIdx.x;
  const int gid = b*256 + t;

  // S0: per-block redundant scale factors (exact: max is order-free)
  {
    double m0 = -1e300, m1 = -1e300;
    for (int i = t; i < 512; i += 256){
      m0 = fmax(m0, C16m[(size_t)i*512 + i]);
      m1 = fmax(m1, C64m[(size_t)i*512 + i]);
    }
    sm.red[t] = m0; __syncthreads();
    for (int o = 128; o; o >>= 1){ if (t < o) sm.red[t] = fmax(sm.red[t], sm.red[t+o]); __syncthreads(); }
    if (t == 0) s_scal0 = 1.0 / fmax(sm.red[0], 1e-300);
    __syncthreads();
    sm.red[t] = m1; __syncthreads();
    for (int o = 128; o; o >>= 1){ if (t < o) sm.red[t] = fmax(sm.red[t], sm.red[t+o]); __syncthreads(); }
    if (t == 0) s_scal1 = 1.0 / fmax(sm.red[0], 1e-300);
    __syncthreads();
  }

  // S1: init V0
  {
    unsigned h = (unsigned)gid * 2654435761u + 12345u;
    h ^= h >> 13; h *= 2246822519u; h ^= h >> 16;
    Va[gid] = ((double)(h & 0xffffu) / 32768.0) - 1.0;
  }
  grid.sync();

  // S2: 2 rounds of C^80 = C^64 * C^16 + Cholesky-QR
  for (int it = 0; it < 2; ++it){
    matv_step(C64m, Va, Vb, s_scal1, gid);
    grid.sync();
    matv_step(C16m, Vb, Va, s_scal0, gid);
    grid.sync();
    // Gram: serial per-entry dot, k ascending (order FROZEN — R8 lesson)
    if (t < 16){
      int e = b*16 + t; int i = e >> 5, j = e & 31;
      double s = 0;
      for (int k = 0; k < 512; ++k) s += Va[(size_t)k*32+i]*Va[(size_t)k*32+j];
      Gm[e] = s;
    }
    grid.sync();
    {
      for (int l = t; l < 1024; l += 256){ int i = l >> 5, j = l & 31; sm.L[i][j] = Gm[l]; }
      __syncthreads();
      for (int k = 0; k < 32; ++k){
        if (t == 0) sm.L[k][k] = sqrt(fmax(sm.L[k][k], 1e-300));
        __syncthreads();
        if (t > k && t < 32) sm.L[t][k] /= sm.L[k][k];
        __syncthreads();
        for (int l = t; l < 1024; l += 256){
          int i = l >> 5, j = l & 31;
          if (i > k && j > k && j <= i) sm.L[i][j] -= sm.L[i][k]*sm.L[j][k];
        }
        __syncthreads();
      }
      if (t < 8){
        int r = b*8 + t;
        double v[32];
        #pragma unroll
        for (int jj = 0; jj < 32; ++jj) v[jj] = Va[(size_t)r*32 + jj];
        #pragma unroll
        for (int jj = 0; jj < 32; ++jj){
          double s = v[jj];
          #pragma unroll
          for (int ii = 0; ii < 32; ++ii) if (ii < jj) s -= sm.L[jj][ii]*v[ii];
          v[jj] = s / sm.L[jj][jj];
        }
        #pragma unroll
        for (int jj = 0; jj < 32; ++jj) Va[(size_t)r*32 + jj] = v[jj];
      }
      __syncthreads();
    }
    grid.sync();
  }

  // S3: Yb = Cm * Va
  matv_step(Cm, Va, Yb, 1.0, gid);
  grid.sync();

  // S4: G = Va^T Yb (serial per-entry, FROZEN order)
  if (t < 16){
    int e = b*16 + t; int i = e >> 5, j = e & 31;
    double s = 0;
    for (int k = 0; k < 512; ++k) s += Va[(size_t)k*32+i]*Yb[(size_t)k*32+j];
    Gm[e] = s;
  }
  grid.sync();

  // S5: Jacobi (block 0 only, 5 sweeps)
  if (b == 0){
    for (int l = t; l < 1024; l += 256){
      int i = l >> 5, j = l & 31;
      sm.jac.G[i][j] = 0.5*(Gm[i*32+j] + Gm[j*32+i]);
      sm.jac.Q[i][j] = (i == j) ? 1.0 : 0.0;
    }
    __syncthreads();
    for (int sweep = 0; sweep < 5; ++sweep)
    for (int r = 0; r < 31; ++r){
      if (t < 16){
        int u = (t == 0) ? 0 : ((r + t - 1) % 31) + 1;
        int v = ((r + 30 - t) % 31) + 1;
        int p_ = u < v ? u : v, q_ = u < v ? v : u;
        double app = sm.jac.G[p_][p_], aqq = sm.jac.G[q_][q_], apq = sm.jac.G[p_][q_];
        double c, s;
        if (fabs(apq) < 1e-280){ c = 1.0; s = 0.0; }
        else {
          double tau = (aqq - app)/(2.0*apq);
          double tt = (tau >= 0 ? 1.0 : -1.0)/(fabs(tau) + sqrt(1.0 + tau*tau));
          c = 1.0/sqrt(1.0 + tt*tt); s = tt*c;
        }
        sm.jac.pcs[t] = c; sm.jac.pss[t] = s; sm.jac.pp[t] = p_; sm.jac.pq[t] = q_;
        sm.jac.map[p_] = t; sm.jac.map[q_] = t | 32;
      }
      __syncthreads();
      for (int l = t; l < 1024; l += 256){
        int i = l >> 5, j = l & 31;
        int mi = sm.jac.map[i], k = mi & 31;
        double c = sm.jac.pcs[k], s = sm.jac.pss[k];
        double gp = sm.jac.G[sm.jac.pp[k]][j], gq = sm.jac.G[sm.jac.pq[k]][j];
        sm.jac.H[i][j] = (mi & 32) ? (s*gp + c*gq) : (c*gp - s*gq);
      }
      __syncthreads();
      for (int l = t; l < 512; l += 256){
        int i = l >> 4, k = l & 15;
        double c = sm.jac.pcs[k], s = sm.jac.pss[k];
        int p_ = sm.jac.pp[k], q_ = sm.jac.pq[k];
        double hp = sm.jac.H[i][p_], hq = sm.jac.H[i][q_];
        sm.jac.G[i][p_] = c*hp - s*hq; sm.jac.G[i][q_] = s*hp + c*hq;
        double qp = sm.jac.Q[i][p_], qq = sm.jac.Q[i][q_];
        sm.jac.Q[i][p_] = c*qp - s*qq; sm.jac.Q[i][q_] = s*qp + c*qq;
      }
      __syncthreads();
    }
    if (t == 0){
      for (int i2 = 0; i2 < 32; ++i2) sm.jac.eig[i2] = sm.jac.G[i2][i2];
      unsigned used = 0;
      for (int k = 0; k < 10; ++k){
        int best = 0; double bv = -1e300;
        for (int i2 = 0; i2 < 32; ++i2)
          if (!((used >> i2) & 1u) && sm.jac.eig[i2] > bv){ bv = sm.jac.eig[i2]; best = i2; }
        used |= 1u << best; sm.jac.idx[k] = best;
      }
    }
    __syncthreads();
    for (int l = t; l < 5120; l += 256){
      int k = l/10, j = l%10;
      int c = sm.jac.idx[j];
      double s2 = 0;
      for (int m = 0; m < 32; ++m) s2 += Va[(size_t)k*32+m]*sm.jac.Q[m][c];
      Pm[k*10+j] = (float)s2;
    }
  }
  grid.sync();

  // S6: feats = xc @ P — LDS-staged, row/thread; accumulation order (c ascending)
  // bitwise identical to the serial version (R8 bundling exonerated this block)
  if (b < 16){
    for (int l = t; l < 5120; l += 256) sm.ft.Ps[l/10][l%10] = Pm[l];
    for (int c = t; c < 512; c += 256) sm.ft.cm[c] = (float)(meanbuf[c]*(1.0/4096.0));
    __syncthreads();
    int r = b*256 + t;
    float acc[10] = {0,0,0,0,0,0,0,0,0,0};
    const float* xr = x + (size_t)r*512;
    for (int c0 = 0; c0 < 512; c0 += 4){
      float4 xv = *(const float4*)&xr[c0];
      float xs[4] = {xv.x, xv.y, xv.z, xv.w};
      #pragma unroll
      for (int q = 0; q < 4; ++q){
        float xc = xs[q] - sm.ft.cm[c0+q];
        #pragma unroll
        for (int j = 0; j < 10; ++j) acc[j] += xc * sm.ft.Ps[c0+q][j];
      }
    }
    #pragma unroll
    for (int j = 0; j < 10; ++j) feats[r*10+j] = acc[j];
  }
  grid.sync();

  // S7: kmeans (FROZEN)
  if (t < 70) sm.km.cs[t/10][t%10] = feats[t];
  if (b < 16){
    int base = b*256;
    for (int i = t; i < 2560; i += 256) sm.km.fs[i/10][i%10] = feats[base*10 + i];
  }
  __syncthreads();
  for (int iter = 0; iter < 10; ++iter){
    float* pbuf = part2 + (size_t)(iter & 1)*16*77;
    if (b < 16){
      float f[10];
      #pragma unroll
      for (int d = 0; d < 10; ++d) f[d] = sm.km.fs[t][d];
      int best = 0; float bd = 3.0e38f;
      for (int k = 0; k < 7; ++k){
        float s = 0;
        #pragma unroll
        for (int d = 0; d < 10; ++d){ float df = f[d]-sm.km.cs[k][d]; s += df*df; }
        if (s < bd){ bd = s; best = k; }
      }
      sm.km.labs[t] = (unsigned char)best;
      __syncthreads();
      if (t < 77){
        float acc = 0;
        if (t < 70){
          int k = t/10, d = t%10;
          for (int nn = 0; nn < 256; ++nn) if (sm.km.labs[nn] == k) acc += sm.km.fs[nn][d];
        } else {
          int k = t - 70;
          for (int nn = 0; nn < 256; ++nn) if (sm.km.labs[nn] == k) acc += 1.f;
        }
        pbuf[b*77 + t] = acc;
      }
    }
    grid.sync();
    if (t < 77){
      float s = 0;
      for (int bb = 0; bb < 16; ++bb) s += pbuf[bb*77 + t];
      sm.km.sums[t] = s;
    }
    __syncthreads();
    if (t < 70){
      float cnt = sm.km.sums[70 + t/10];
      if (cnt > 0.f) sm.km.cs[t/10][t%10] = sm.km.sums[t] / fmaxf(cnt, 1.f);
    }
    __syncthreads();
  }
  if (b < 16){
    float f[10];
    #pragma unroll
    for (int d = 0; d < 10; ++d) f[d] = sm.km.fs[t][d];
    float bd = 3.0e38f;
    for (int k = 0; k < 7; ++k){
      float s = 0;
      #pragma unroll
      for (int d = 0; d < 10; ++d){ float df = f[d]-sm.km.cs[k][d]; s += df*df; }
      bd = fminf(bd, s);
    }
    distb[b*256 + t] = sqrtf(bd);
  }
  grid.sync();

  // S8: exact median (radix select) + keep, block 0 only (FROZEN)
  if (b == 0){
    for (int i = t; i < 4096; i += 256) sm.med.u[i] = __float_as_uint(distb[i]);
    __syncthreads();
    unsigned vals[2];
    for (int ri = 0; ri < 2; ++ri){
      int r = 2047 + ri;
      unsigned prefix = 0;
      for (int bit = 31; bit >= 0; --bit){
        unsigned hm = (bit < 31) ? (0xffffffffu << (bit+1)) : 0u;
        int c = 0;
        for (int i = t; i < 4096; i += 256){
          unsigned e = sm.med.u[i];
          if ((e & hm) == prefix && !((e >> bit) & 1u)) c++;
        }
        #pragma unroll
        for (int o = 32; o; o >>= 1) c += __shfl_xor(c, o, 64);
        if ((t & 63) == 0) sm.med.redc[t >> 6] = c;
        __syncthreads();
        int tot = sm.med.redc[0] + sm.med.redc[1] + sm.med.redc[2] + sm.med.redc[3];
        if (r >= tot){ prefix |= (1u << bit); r -= tot; }
        __syncthreads();
      }
      vals[ri] = prefix;
    }
    float med = 0.5f*(__uint_as_float(vals[0]) + __uint_as_float(vals[1]));
    for (int i = t; i < 4096; i += 256) keep[i] = (distb[i] <= med) ? 1.f : 0.f;
  }
}

// ---------------- launch ----------------
extern "C" void kernel_launch(void* const* d_in, const int* in_sizes, int n_in,
                              void* d_out, int out_size, void* d_ws, size_t ws_size,
                              hipStream_t stream){
  const float* x      = (const float*)d_in[0];
  const float* W_ego  = (const float*)d_in[1];
  const float* b_ego  = (const float*)d_in[2];
  const float* W_cos  = (const float*)d_in[3];
  const float* b_cos  = (const float*)d_in[4];
  const float* W_glob = (const float*)d_in[5];
  const float* b_glob = (const float*)d_in[6];
  const float* W_fc   = (const float*)d_in[7];
  const float* b_fc   = (const float*)d_in[8];
  const int*   ei     = (const int*)d_in[9];
  const int* src = ei;
  const int* dst = ei + NE;
  float* out = (float*)d_out;

  char* p = (char*)d_ws;
  auto alloc = [&](size_t n) -> char* { char* r = p; p += (n + 255) & ~(size_t)255; return r; };

  unsigned long long* B1 = (unsigned long long*)alloc((size_t)NN*64*8);
  unsigned short* Mf     = (unsigned short*)alloc((size_t)NN*NN*2);
  unsigned short* x_bf   = (unsigned short*)alloc((size_t)NN*NC*2);
  unsigned short* xT_bf  = (unsigned short*)alloc((size_t)NN*NC*2);
  unsigned short* egof   = (unsigned short*)alloc((size_t)NN*NC*2);
  unsigned short* cosf   = (unsigned short*)alloc((size_t)NN*NC*2);
  unsigned short* h_ego  = (unsigned short*)alloc((size_t)NN*NC*2);
  unsigned short* h_cos  = (unsigned short*)alloc((size_t)NN*NC*2);
  unsigned short* WegoT  = (unsigned short*)alloc((size_t)512*512*2);
  unsigned short* WcosT  = (unsigned short*)alloc((size_t)512*512*2);
  unsigned short* WglobT = (unsigned short*)alloc((size_t)512*512*2);
  unsigned short* WfcT   = (unsigned short*)alloc((size_t)128*2048*2);
  unsigned short* comb   = (unsigned short*)alloc((size_t)NN*2048*2);
  float* rowrecip = (float*)alloc((size_t)NN*4);
  float* keep     = (float*)alloc((size_t)NN*4);
  float* invn     = (float*)alloc((size_t)NN*4);
  int* cnt_in   = (int*)alloc((size_t)NN*4);
  int* cnt_out  = (int*)alloc((size_t)NN*4);
  int* off_in   = (int*)alloc((size_t)(NN+1)*4);
  int* off_out  = (int*)alloc((size_t)(NN+1)*4);
  int* fill_in  = (int*)alloc((size_t)NN*4);
  int* fill_out = (int*)alloc((size_t)NN*4);
  int* csr_in   = (int*)alloc((size_t)NE*4);
  int* csr_out  = (int*)alloc((size_t)NE*4);
  double* meanbuf = (double*)alloc(512*8);
  double* Cm  = (double*)alloc((size_t)512*512*8);
  double* C2m = (double*)alloc((size_t)512*512*8);
  double* C4m = (double*)alloc((size_t)512*512*8);
  double* C8m = (double*)alloc((size_t)512*512*8);
  double* C16m = (double*)alloc((size_t)512*512*8);
  double* C32m = (double*)alloc((size_t)512*512*8);
  double* C64m = (double*)alloc((size_t)512*512*8);
  double* Va  = (double*)alloc((size_t)512*32*8);
  double* Vb  = (double*)alloc((size_t)512*32*8);
  double* Yb  = (double*)alloc((size_t)512*32*8);
  double* Gm  = (double*)alloc(32*32*8);
  float* Pm    = (float*)alloc((size_t)512*10*4);
  float* feats = (float*)alloc((size_t)NN*10*4);
  float* part  = (float*)alloc((size_t)2*16*77*4);
  float* distb = (float*)alloc((size_t)NN*4);

  // fused zeroing (WfcT intentionally left poisoned: rows >=40 only feed discarded cols)
  k_zero<<<1024, 256, 0, stream>>>(B1, cnt_in, cnt_out, meanbuf);

  // conversions
  k_transconv<<<dim3(8,64), 256, 0, stream>>>(x, NN, NC, xT_bf, NN, x_bf);
  k_transconv3<<<dim3(8,8,3), 256, 0, stream>>>(W_ego, W_cos, W_glob, WegoT, WcosT, WglobT);
  k_transconv<<<dim3(1,32), 256, 0, stream>>>(W_fc, 2048, 40, WfcT, 2048, (unsigned short*)0);
  k_invnorm<<<1024, 256, 0, stream>>>(x, invn);

  // CSR + bitsets (fused edge pass)
  k_count_b1<<<512, 256, 0, stream>>>(src, dst, cnt_in, cnt_out, B1);
  k_scan<<<1, 1024, 0, stream>>>(cnt_in, cnt_out, off_in, off_out, fill_in, fill_out);
  k_fill<<<512, 256, 0, stream>>>(src, dst, fill_in, fill_out, csr_in, csr_out);
  k_bits2<<<1024, 256, 0, stream>>>(B1, off_in, csr_in, Mf, rowrecip);

  // ego_feats = (Mf @ x) / rowsum
  gemm_bt<0><<<dim3(64,4), 256, 0, stream>>>(Mf, NN, xT_bf, NN, NN, NC,
      (float*)0, egof, NC, (const float*)0, rowrecip);

  // dominant branch: big fp64 pieces (symmetric triangular + mirror)
  k_colmean<<<32, 256, 0, stream>>>(x, meanbuf);
  k_cov<<<dim3(16,16), 256, 0, stream>>>(x, meanbuf, Cm);
  k_mm64<<<dim3(16,16), 256, 0, stream>>>(Cm,  Cm,  C2m);
  k_mm64<<<dim3(16,16), 256, 0, stream>>>(C2m, C2m, C4m);
  k_mm64<<<dim3(16,16), 256, 0, stream>>>(C4m, C4m, C8m);
  k_mm64<<<dim3(16,16), 256, 0, stream>>>(C8m, C8m, C16m);
  k_mm64<<<dim3(16,16), 256, 0, stream>>>(C16m, C16m, C32m);
  k_mm64<<<dim3(16,16), 256, 0, stream>>>(C32m, C32m, C64m);

  // fused cooperative tail (keep-path numerics frozen)
  {
    void* args[] = { (void*)&Cm, (void*)&C16m, (void*)&C64m, (void*)&Va, (void*)&Vb,
                     (void*)&Yb, (void*)&Gm, (void*)&x, (void*)&meanbuf, (void*)&Pm,
                     (void*)&feats, (void*)&part, (void*)&distb, (void*)&keep };
    hipLaunchCooperativeKernel((void*)k_tail, dim3(64), dim3(256), args, 0, stream);
  }

  // cosine branch (single-pass, inv-norm form)
  k_cos<<<1024, 256, 0, stream>>>(x_bf, invn, off_out, csr_out, cosf);

  // encoders (three GEMMs in one launch, z selects)
  gemm_bt3<<<dim3(64,4,3), 256, 0, stream>>>(
      egof, cosf, x_bf,
      WegoT, WcosT, WglobT,
      b_ego, b_cos, b_glob,
      h_ego, h_cos, comb + 1536,
      2048);

  // aggregation + cut into combined (fused)
  k_aggcut<<<1024, 256, 0, stream>>>(h_ego, h_cos, off_in, csr_in, x_bf, keep, comb);

  // head GEMM + fused log_softmax
  gemm_head<<<64, 256, 0, stream>>>(comb, WfcT, b_fc, out);
}